// Round 5
// baseline (1283.669 us; speedup 1.0000x reference)
//
#include <hip/hip_runtime.h>
#include <hip/hip_bf16.h>

typedef unsigned short u16t;

__device__ __forceinline__ float bfu(u16t u) {
    union { unsigned int i; float f; } c;
    c.i = ((unsigned int)u) << 16;
    return c.f;
}
__device__ __forceinline__ u16t fbf(float f) {
    __hip_bfloat16 h = __float2bfloat16(f);
    return *reinterpret_cast<u16t*>(&h);
}

// ---------------------------------------------------------------------------
// Fused BN + LeakyReLU + 3x3 conv, register-blocked.
// 128-t tile per block, C staged in 32-channel chunks (~51 KB LDS -> 3
// blocks/CU).  Each thread: CO_T consecutive out-channels x 8 t (fp32 accs).
// Per input channel: 3*3*CO_T*8 FMAs vs 12 LDS reads + 9*CO_T L1 weight
// loads -> ~80% FMA issue.
// ---------------------------------------------------------------------------
template<int C_IN, int C_OUT>
__global__ __launch_bounds__(256) void bn_conv3x3_k(
    const float* __restrict__ src0, const float* __restrict__ src1,
    const float* __restrict__ src2,
    const float* __restrict__ gg, const float* __restrict__ bb,
    const float* __restrict__ mm, const float* __restrict__ vv,
    const float* __restrict__ w,  const float* __restrict__ wb,
    float* __restrict__ dst)
{
    constexpr int F = 64, T = 512, TT = 128;
    constexpr int LW = TT + 2;            // 130 valid columns
    constexpr int PITCH = TT + 4;         // 132 -> 16B-aligned rows
    constexpr int CH = 32;                // channels per LDS chunk
    constexpr int NCHUNK = C_IN / CH;     // 2,3,4
    constexpr int NT = 8;                 // t per thread
    constexpr int NTG = 16;               // t-groups (tid & 15)
    constexpr int NCG = 16;               // co-groups (tid >> 4)
    constexpr int CO_T = C_OUT / NCG;     // 4 (C_OUT=64) or 2 (C_OUT=32)

    __shared__ float s_in[CH][3][PITCH];
    __shared__ float s_sc[C_IN], s_sh[C_IN];

    const int tid = threadIdx.x;
    const int t0 = blockIdx.x * TT;
    const int f  = blockIdx.y;
    const int b  = blockIdx.z;

    if (tid < C_IN) {
        float sc = gg[tid] * rsqrtf(vv[tid] + 1e-5f);
        s_sc[tid] = sc;
        s_sh[tid] = bb[tid] - mm[tid] * sc;
    }

    const int tg = tid & 15;
    const int cg = tid >> 4;
    const int tb = tg * NT;

    float acc[CO_T][NT];
#pragma unroll
    for (int i = 0; i < CO_T; i++)
#pragma unroll
        for (int j = 0; j < NT; j++) acc[i][j] = 0.f;

    for (int ch = 0; ch < NCHUNK; ch++) {
        __syncthreads();   // sc/sh ready (ch=0) / prev chunk consumed (ch>0)

        // stage chunk [ch*CH, ch*CH+CH): 3 rows x 130 cols, normalized
        for (int idx = tid; idx < CH * 3 * LW; idx += 256) {
            int c  = idx / (3 * LW);
            int r  = idx - c * (3 * LW);
            int kh = r / LW;
            int tt = r - kh * LW;
            int gc = ch * CH + c;
            int fi = f + kh - 1;
            int ti = t0 + tt - 1;
            float val = 0.f;
            if ((unsigned)fi < (unsigned)F && (unsigned)ti < (unsigned)T) {
                float xv;
                if (gc < 64) {
                    xv = src0[(((long)b * 64 + gc) * F + fi) * T + ti];
                } else if (C_IN > 96 && gc >= 96) {
                    xv = src2[(((long)b * 32 + (gc - 96)) * F + fi) * T + ti];
                } else {
                    xv = src1[(((long)b * 32 + (gc - 64)) * F + fi) * T + ti];
                }
                float xn = xv * s_sc[gc] + s_sh[gc];
                val = (xn >= 0.f) ? xn : 0.01f * xn;
            }
            s_in[c][kh][tt] = val;
        }
        __syncthreads();

        for (int c = 0; c < CH; c++) {
            const int gc = ch * CH + c;
            // hoist all weights for this input channel (L1-resident)
            float wreg[CO_T][9];
#pragma unroll
            for (int i = 0; i < CO_T; i++) {
                const float* wp = &w[((cg * CO_T + i) * C_IN + gc) * 9];
#pragma unroll
                for (int k = 0; k < 9; k++) wreg[i][k] = wp[k];
            }
#pragma unroll
            for (int kh = 0; kh < 3; kh++) {
                const float* row = &s_in[c][kh][tb];
                float vr[NT + 2];
                float4 q0 = *(const float4*)(row);
                float4 q1 = *(const float4*)(row + 4);
                vr[0]=q0.x; vr[1]=q0.y; vr[2]=q0.z; vr[3]=q0.w;
                vr[4]=q1.x; vr[5]=q1.y; vr[6]=q1.z; vr[7]=q1.w;
                vr[8] = row[8];
                vr[9] = row[9];
#pragma unroll
                for (int i = 0; i < CO_T; i++) {
                    float w0 = wreg[i][kh*3+0];
                    float w1 = wreg[i][kh*3+1];
                    float w2 = wreg[i][kh*3+2];
#pragma unroll
                    for (int j = 0; j < NT; j++)
                        acc[i][j] += vr[j]*w0 + vr[j+1]*w1 + vr[j+2]*w2;
                }
            }
        }
    }

#pragma unroll
    for (int i = 0; i < CO_T; i++) {
        const int co = cg * CO_T + i;
        const float bias = wb[co];
        float* op = &dst[(((long)b * C_OUT + co) * F + f) * T + t0 + tb];
        float4 o0, o1;
        o0.x=acc[i][0]+bias; o0.y=acc[i][1]+bias; o0.z=acc[i][2]+bias; o0.w=acc[i][3]+bias;
        o1.x=acc[i][4]+bias; o1.y=acc[i][5]+bias; o1.z=acc[i][6]+bias; o1.w=acc[i][7]+bias;
        *(float4*)(op)     = o0;
        *(float4*)(op + 4) = o1;
    }
}

// ---------------------------------------------------------------------------
// Fused qkv-projection + banded local attention.  One block per (h,f,b),
// 512 threads = query positions.  K and V in bf16 LDS, transposed [d][t]
// (stride-1 across lanes -> conflict-free).  Phantom zero-keys for t<64:
// init m=0, l=64-t.  ~46 KB LDS -> 3 blocks/CU.
// ---------------------------------------------------------------------------
__global__ __launch_bounds__(512) void attn_fused_k(
    const float* __restrict__ y, const float* __restrict__ qw,
    const float* __restrict__ qb, float* __restrict__ o)
{
    constexpr int F = 64, T = 512;
    const int h = blockIdx.x, f = blockIdx.y, b = blockIdx.z;
    const int t = threadIdx.x;

    __shared__ float s_wT[64][48];              // [c][kind*16+d]
    __shared__ float s_b[48];
    __shared__ u16t  s_kT[16][T + 8];           // bf16, transposed
    __shared__ u16t  s_vT[16][T + 8];

    for (int i = t; i < 64 * 48; i += 512) {
        int c = i / 48, r = i - c * 48;
        int kind = r >> 4, d = r & 15;
        s_wT[c][r] = qw[(kind * 64 + h * 16 + d) * 64 + c];
    }
    if (t < 48) {
        int kind = t >> 4, d = t & 15;
        s_b[t] = qb[kind * 64 + h * 16 + d];
    }
    __syncthreads();

    float acc[48];
#pragma unroll
    for (int r = 0; r < 48; r++) acc[r] = s_b[r];

    const long chs = (long)F * T;
    const long ybase = (long)b * 64 * chs + (long)f * T + t;
    for (int c = 0; c < 64; c++) {
        float yv = y[ybase + (long)c * chs];
        const float4* wrow = (const float4*)(&s_wT[c][0]);
#pragma unroll
        for (int r4 = 0; r4 < 12; r4++) {
            float4 w4 = wrow[r4];
            acc[r4*4+0] += w4.x * yv;
            acc[r4*4+1] += w4.y * yv;
            acc[r4*4+2] += w4.z * yv;
            acc[r4*4+3] += w4.w * yv;
        }
    }
#pragma unroll
    for (int d = 0; d < 16; d++) {
        s_kT[d][t] = fbf(acc[16 + d]);
        s_vT[d][t] = fbf(acc[32 + d]);
    }
    float q[16];
#pragma unroll
    for (int d = 0; d < 16; d++) q[d] = 0.25f * acc[d];  // fold 1/sqrt(16)
    __syncthreads();

    const int n_neg = (t < 64) ? (64 - t) : 0;
    float m = (n_neg > 0) ? 0.f : -3.0e38f;
    float l = (float)n_neg;
    float oa[16];
#pragma unroll
    for (int d = 0; d < 16; d++) oa[d] = 0.f;

    const int p0 = (t >= 64) ? (t - 64) : 0;
    const int p1 = (t + 64 <= T - 1) ? (t + 64) : (T - 1);

    for (int p = p0; p <= p1; p++) {
        float s = 0.f;
#pragma unroll
        for (int d = 0; d < 16; d++) s += q[d] * bfu(s_kT[d][p]);

        float mn = fmaxf(m, s);
        float em = __expf(m - mn);
        float es = __expf(s - mn);
        l = l * em + es;
#pragma unroll
        for (int d = 0; d < 16; d++)
            oa[d] = oa[d] * em + es * bfu(s_vT[d][p]);
        m = mn;
    }
    const float inv = 1.0f / l;
#pragma unroll
    for (int d = 0; d < 16; d++)
        o[(((long)b * 64 + h * 16 + d) * F + f) * T + t] = oa[d] * inv;
}

// ---------------------------------------------------------------------------
// Fused o-projection + BN + LeakyReLU + final conv1x1.  All fp32.
// ---------------------------------------------------------------------------
__global__ __launch_bounds__(256) void oproj_final_k(
    const float* __restrict__ ob, const float* __restrict__ y,
    const float* __restrict__ ow, const float* __restrict__ obias,
    const float* __restrict__ sg, const float* __restrict__ sb,
    const float* __restrict__ sm, const float* __restrict__ sv,
    const float* __restrict__ sw, const float* __restrict__ swb,
    float* __restrict__ out)
{
    constexpr int F = 64, T = 512;
    __shared__ float s_ob[64][64];
    __shared__ float s_y2[64][64];   // bn_lrelu'd y half
    __shared__ float s_att[64][64];  // bn_lrelu'd att half
    __shared__ float s_sc[128], s_sh[128];

    const int tid = threadIdx.x;
    const int t0 = blockIdx.x * 64;
    const int f = blockIdx.y, b = blockIdx.z;

    if (tid < 128) {
        float sc = sg[tid] * rsqrtf(sv[tid] + 1e-5f);
        s_sc[tid] = sc;
        s_sh[tid] = sb[tid] - sm[tid] * sc;
    }
    __syncthreads();

    for (int i = tid; i < 64 * 64; i += 256) {
        int c = i >> 6, tt = i & 63;
        long gi = (((long)b * 64 + c) * F + f) * T + t0 + tt;
        s_ob[c][tt] = ob[gi];
        float yv = y[gi];
        float xn = yv * s_sc[c] + s_sh[c];
        s_y2[c][tt] = (xn >= 0.f) ? xn : 0.01f * xn;
    }
    __syncthreads();

    const int t  = tid & 63;
    const int wv = tid >> 6;       // 4 groups x 16 out-channels

    float acc[16];
#pragma unroll
    for (int i = 0; i < 16; i++) acc[i] = obias[wv * 16 + i];
    for (int c = 0; c < 64; c++) {
        float v = s_ob[c][t];
#pragma unroll
        for (int i = 0; i < 16; i++)
            acc[i] += ow[(wv * 16 + i) * 64 + c] * v;
    }
#pragma unroll
    for (int i = 0; i < 16; i++) {
        int oc = wv * 16 + i;
        float xn = acc[i] * s_sc[64 + oc] + s_sh[64 + oc];
        s_att[oc][t] = (xn >= 0.f) ? xn : 0.01f * xn;
    }
    __syncthreads();

    float acc2[16];
#pragma unroll
    for (int i = 0; i < 16; i++) acc2[i] = swb[wv * 16 + i];
    for (int c = 0; c < 64; c++) {
        float v0 = s_y2[c][t];
        float v1 = s_att[c][t];
#pragma unroll
        for (int i = 0; i < 16; i++) {
            const float* wr = &sw[(wv * 16 + i) * 128];
            acc2[i] += wr[c] * v0 + wr[64 + c] * v1;
        }
    }
#pragma unroll
    for (int i = 0; i < 16; i++)
        out[(((long)b * 64 + wv * 16 + i) * F + f) * T + t0 + t] = acc2[i];
}

// ---------------------------------------------------------------------------
extern "C" void kernel_launch(void* const* d_in, const int* in_sizes, int n_in,
                              void* d_out, int out_size, void* d_ws, size_t ws_size,
                              hipStream_t stream)
{
    (void)in_sizes; (void)n_in; (void)out_size; (void)ws_size;

    const float* x      = (const float*)d_in[0];
    const float* bd0_g  = (const float*)d_in[1];
    const float* bd0_b  = (const float*)d_in[2];
    const float* bd0_m  = (const float*)d_in[3];
    const float* bd0_v  = (const float*)d_in[4];
    const float* bd0_w  = (const float*)d_in[5];
    const float* bd0_wb = (const float*)d_in[6];
    const float* bd1_g  = (const float*)d_in[7];
    const float* bd1_b  = (const float*)d_in[8];
    const float* bd1_m  = (const float*)d_in[9];
    const float* bd1_v  = (const float*)d_in[10];
    const float* bd1_w  = (const float*)d_in[11];
    const float* bd1_wb = (const float*)d_in[12];
    const float* bdo_g  = (const float*)d_in[13];
    const float* bdo_b  = (const float*)d_in[14];
    const float* bdo_m  = (const float*)d_in[15];
    const float* bdo_v  = (const float*)d_in[16];
    const float* bdo_w  = (const float*)d_in[17];
    const float* bdo_wb = (const float*)d_in[18];
    const float* qkv_w  = (const float*)d_in[19];
    const float* qkv_b  = (const float*)d_in[20];
    const float* o_w    = (const float*)d_in[21];
    const float* o_b    = (const float*)d_in[22];
    const float* sao_g  = (const float*)d_in[23];
    const float* sao_b  = (const float*)d_in[24];
    const float* sao_m  = (const float*)d_in[25];
    const float* sao_v  = (const float*)d_in[26];
    const float* sao_w  = (const float*)d_in[27];
    const float* sao_wb = (const float*)d_in[28];

    char* ws = (char*)d_ws;
    // fp32 intermediates, peak 67.1 MB (ws >= 84MB proven):
    //   [0, 16.8M)    a0   (later reused by ob)
    //   [16.8, 33.6M) a1   (later reused by ob)
    //   [33.6, 67.1M) y
    float* a0  = (float*)(ws);
    float* a1  = (float*)(ws + 16777216);
    float* y   = (float*)(ws + 33554432);
    float* ob  = (float*)(ws);            // 33.6M, over a0+a1 (dead after y)

    dim3 blk(256);
    dim3 g3(4, 64, 4);    // T/128, F, B

    hipLaunchKernelGGL((bn_conv3x3_k<64, 32>), g3, blk, 0, stream,
        x, nullptr, nullptr, bd0_g, bd0_b, bd0_m, bd0_v, bd0_w, bd0_wb, a0);
    hipLaunchKernelGGL((bn_conv3x3_k<96, 32>), g3, blk, 0, stream,
        x, a0, nullptr, bd1_g, bd1_b, bd1_m, bd1_v, bd1_w, bd1_wb, a1);
    hipLaunchKernelGGL((bn_conv3x3_k<128, 64>), g3, blk, 0, stream,
        x, a0, a1, bdo_g, bdo_b, bdo_m, bdo_v, bdo_w, bdo_wb, y);
    hipLaunchKernelGGL(attn_fused_k, dim3(4, 64, 4), dim3(512), 0, stream,
        y, qkv_w, qkv_b, ob);
    hipLaunchKernelGGL(oproj_final_k, dim3(8, 64, 4), blk, 0, stream,
        ob, y, o_w, o_b, sao_g, sao_b, sao_m, sao_v, sao_w, sao_wb,
        (float*)d_out);
}

// Round 6
// 611.594 us; speedup vs baseline: 2.0989x; 2.0989x over previous
//
#include <hip/hip_runtime.h>
#include <hip/hip_bf16.h>

typedef unsigned short u16t;
typedef __attribute__((ext_vector_type(8))) short bfrag;      // 8 bf16 bits
typedef __attribute__((ext_vector_type(4))) float f32x4;      // MFMA acc
typedef __attribute__((ext_vector_type(8))) unsigned short uh8;

__device__ __forceinline__ float bfu(u16t u) {
    union { unsigned int i; float f; } c;
    c.i = ((unsigned int)u) << 16;
    return c.f;
}
__device__ __forceinline__ u16t fbf(float f) {
    __hip_bfloat16 h = __float2bfloat16(f);
    return *reinterpret_cast<u16t*>(&h);
}

// ---------------------------------------------------------------------------
// x [b][64c][64f][512t] fp32  ->  x_t [b][f][t][64c] bf16
// ---------------------------------------------------------------------------
__global__ __launch_bounds__(256) void prep_x_k(
    const float* __restrict__ x, u16t* __restrict__ xt)
{
    constexpr int F = 64, T = 512;
    __shared__ u16t su[64][74];   // pitch 74 -> conflict-free col reads
    const int tid = threadIdx.x;
    const int t0 = blockIdx.x * 64;
    const int f = blockIdx.y, b = blockIdx.z;

#pragma unroll
    for (int p = 0; p < 16; p++) {
        int i = tid + 256 * p;
        int c = i >> 6, t = i & 63;
        su[c][t] = fbf(x[(((long)b * 64 + c) * F + f) * T + t0 + t]);
    }
    __syncthreads();
#pragma unroll
    for (int p = 0; p < 2; p++) {
        int i = tid + 256 * p;
        int t = i >> 3, c8 = i & 7;
        uh8 v;
#pragma unroll
        for (int j = 0; j < 8; j++) v[j] = su[c8 * 8 + j][t];
        *(uh8*)&xt[(((long)b * F + f) * T + t0 + t) * 64 + c8 * 8] = v;
    }
}

// ---------------------------------------------------------------------------
// Pack conv weights fp32 [co][c][3][3] -> bf16 [(kh*3+kw)][cb][co][32]
// segments: conv0 @0 (18432), conv1 @18432 (27648), conv2 @46080 (73728)
// ---------------------------------------------------------------------------
__global__ __launch_bounds__(256) void prep_w_k(
    const float* __restrict__ w0, const float* __restrict__ w1,
    const float* __restrict__ w2, u16t* __restrict__ wp)
{
    int idx = blockIdx.x * 256 + threadIdx.x;
    if (idx >= 119808) return;
    int C_IN, C_OUT, e;
    const float* src;
    if (idx < 18432)      { C_IN = 64;  C_OUT = 32; src = w0; e = idx; }
    else if (idx < 46080) { C_IN = 96;  C_OUT = 32; src = w1; e = idx - 18432; }
    else                  { C_IN = 128; C_OUT = 64; src = w2; e = idx - 46080; }
    int NCB = C_IN / 32;
    int ks = e & 31;
    int e2 = e >> 5;
    int co = e2 % C_OUT;
    int e3 = e2 / C_OUT;
    int cb = e3 % NCB;
    int kk = e3 / NCB;
    int c  = cb * 32 + ks;
    int kh = kk / 3, kw = kk % 3;
    wp[idx] = fbf(src[((co * C_IN + c) * 3 + kh) * 3 + kw]);
}

// ---------------------------------------------------------------------------
// MFMA fused BN + LeakyReLU + 3x3 conv.
// Inputs c-contiguous bf16: s0 = x_t (64c), s1 = a0 (32c), s2 = a1 (32c).
// Stage normalized tile s_x[3][66][C+8] bf16; 4 waves = 4 t-subtiles of 16;
// each wave accumulates all C_OUT via 16x16x32 bf16 MFMA; K = c (8
// consecutive c per lane = one ds_read_b128).  Output [b][f][t][C_OUT].
// ---------------------------------------------------------------------------
template<int C_IN, int C_OUT, bool OBF>
__global__ __launch_bounds__(256) void conv3x3_mfma_k(
    const u16t* __restrict__ s0, const u16t* __restrict__ s1,
    const u16t* __restrict__ s2,
    const float* __restrict__ gg, const float* __restrict__ bb,
    const float* __restrict__ mm, const float* __restrict__ vv,
    const u16t* __restrict__ wseg, const float* __restrict__ wb,
    void* __restrict__ dstv)
{
    constexpr int F = 64, T = 512, TT = 64;
    constexpr int CP = C_IN + 8;
    constexpr int NCB = C_IN / 32;
    constexpr int NCOT = C_OUT / 16;
    constexpr int CS = C_IN / 8;
    constexpr int CSP = (CS <= 8) ? 8 : 16;
    constexpr int RPP = 256 / CSP;
    constexpr int NPASS = (198 + RPP - 1) / RPP;

    __shared__ __align__(16) u16t s_x[3][66][CP];

    const int tid = threadIdx.x;
    const int t0 = blockIdx.x * TT;
    const int f  = blockIdx.y;
    const int b  = blockIdx.z;

    const int c8 = tid % CSP;
    const int r0 = tid / CSP;
    const bool cok = (c8 < CS);

    float sc[8], sh[8];
    if (cok) {
#pragma unroll
        for (int j = 0; j < 8; j++) {
            int c = c8 * 8 + j;
            float s = gg[c] * rsqrtf(vv[c] + 1e-5f);
            sc[j] = s;
            sh[j] = bb[c] - mm[c] * s;
        }
    }

    for (int p = 0; p < NPASS; p++) {
        int row = r0 + p * RPP;
        if (row < 198 && cok) {
            int kh = (row >= 132) ? 2 : ((row >= 66) ? 1 : 0);
            int tp = row - kh * 66;
            int fi = f + kh - 1;
            int tg = t0 + tp - 1;
            uh8 v = (uh8)0;
            if ((unsigned)fi < (unsigned)F && (unsigned)tg < (unsigned)T) {
                const u16t* sp; int coff, cw;
                if (c8 < 8)       { sp = s0; coff = c8 * 8;        cw = 64; }
                else if (c8 < 12) { sp = s1; coff = (c8 - 8) * 8;  cw = 32; }
                else              { sp = s2; coff = (c8 - 12) * 8; cw = 32; }
                uh8 raw = *(const uh8*)&sp[(((long)b * F + fi) * T + tg) * cw + coff];
#pragma unroll
                for (int j = 0; j < 8; j++) {
                    float xv = bfu(raw[j]);
                    float xn = fmaf(xv, sc[j], sh[j]);
                    v[j] = fbf(fmaxf(xn, 0.01f * xn));   // lrelu = max(x, .01x)
                }
            }
            *(uh8*)&s_x[kh][tp][c8 * 8] = v;
        }
    }
    __syncthreads();

    const int l  = tid & 63;
    const int wv = tid >> 6;      // wave = t-subtile
    const int lr = l & 15;
    const int lq = l >> 4;

    f32x4 acc[NCOT];
#pragma unroll
    for (int i = 0; i < NCOT; i++) acc[i] = (f32x4){0.f, 0.f, 0.f, 0.f};

    const int tbase = wv * 16 + lr;
    const int cbase = lq * 8;
    const int aoff  = lr * 32 + lq * 8;

    int it = 0;
#pragma unroll
    for (int kh = 0; kh < 3; kh++)
#pragma unroll
    for (int kw = 0; kw < 3; kw++)
#pragma unroll
    for (int cb = 0; cb < NCB; cb++) {
        bfrag B = *(const bfrag*)&s_x[kh][tbase + kw][cb * 32 + cbase];
#pragma unroll
        for (int ct = 0; ct < NCOT; ct++) {
            bfrag A = *(const bfrag*)&wseg[(it * C_OUT + ct * 16) * 32 + aoff];
            acc[ct] = __builtin_amdgcn_mfma_f32_16x16x32_bf16(A, B, acc[ct], 0, 0, 0);
        }
        it++;
    }

    const int t = t0 + wv * 16 + lr;
#pragma unroll
    for (int ct = 0; ct < NCOT; ct++) {
        int co0 = ct * 16 + lq * 4;        // D row = (l>>4)*4 + j
        float4 bs = *(const float4*)&wb[co0];
        long obase = (((long)b * F + f) * T + t) * C_OUT + co0;
        if (OBF) {
            u16t* dp = (u16t*)dstv;
            ushort4 pk;
            pk.x = fbf(acc[ct][0] + bs.x);
            pk.y = fbf(acc[ct][1] + bs.y);
            pk.z = fbf(acc[ct][2] + bs.z);
            pk.w = fbf(acc[ct][3] + bs.w);
            *(ushort4*)&dp[obase] = pk;
        } else {
            float* dp = (float*)dstv;
            float4 ov;
            ov.x = acc[ct][0] + bs.x;
            ov.y = acc[ct][1] + bs.y;
            ov.z = acc[ct][2] + bs.z;
            ov.w = acc[ct][3] + bs.w;
            *(float4*)&dp[obase] = ov;
        }
    }
}

// ---------------------------------------------------------------------------
// Fused qkv-projection + banded local attention.  y fp32 [b][f][t][64].
// K bf16 LDS, V fp32 LDS, both [d][t] (stride-1 lane reads).  Phantom
// zero-keys for t<64: init m=0, l=64-t.  Output ob fp32 [b][f][t][64].
// ---------------------------------------------------------------------------
__global__ __launch_bounds__(512) void attn_fused_k(
    const float* __restrict__ y, const float* __restrict__ qw,
    const float* __restrict__ qb, float* __restrict__ o)
{
    constexpr int F = 64, T = 512;
    const int h = blockIdx.x, f = blockIdx.y, b = blockIdx.z;
    const int t = threadIdx.x;

    __shared__ float s_wT[64][48];
    __shared__ float s_b[48];
    __shared__ u16t  s_kT[16][T + 8];
    __shared__ float s_vT[16][T + 8];

    for (int i = t; i < 64 * 48; i += 512) {
        int c = i / 48, r = i - c * 48;
        int kind = r >> 4, d = r & 15;
        s_wT[c][r] = qw[(kind * 64 + h * 16 + d) * 64 + c];
    }
    if (t < 48) {
        int kind = t >> 4, d = t & 15;
        s_b[t] = qb[kind * 64 + h * 16 + d];
    }
    __syncthreads();

    float acc[48];
#pragma unroll
    for (int r = 0; r < 48; r++) acc[r] = s_b[r];

    const float* yrow = y + ((long)(b * F + f) * T + t) * 64;
#pragma unroll 4
    for (int c4 = 0; c4 < 16; c4++) {
        float4 y4 = ((const float4*)yrow)[c4];
#pragma unroll
        for (int k = 0; k < 4; k++) {
            float yv = (k == 0) ? y4.x : (k == 1) ? y4.y : (k == 2) ? y4.z : y4.w;
            const float4* wrow = (const float4*)(&s_wT[c4 * 4 + k][0]);
#pragma unroll
            for (int r4 = 0; r4 < 12; r4++) {
                float4 w4 = wrow[r4];
                acc[r4*4+0] += w4.x * yv;
                acc[r4*4+1] += w4.y * yv;
                acc[r4*4+2] += w4.z * yv;
                acc[r4*4+3] += w4.w * yv;
            }
        }
    }
#pragma unroll
    for (int d = 0; d < 16; d++) {
        s_kT[d][t] = fbf(acc[16 + d]);
        s_vT[d][t] = acc[32 + d];
    }
    float q[16];
#pragma unroll
    for (int d = 0; d < 16; d++) q[d] = 0.25f * acc[d];  // fold 1/sqrt(16)
    __syncthreads();

    const int n_neg = (t < 64) ? (64 - t) : 0;
    float m = (n_neg > 0) ? 0.f : -3.0e38f;
    float l = (float)n_neg;
    float oa[16];
#pragma unroll
    for (int d = 0; d < 16; d++) oa[d] = 0.f;

    const int p0 = (t >= 64) ? (t - 64) : 0;
    const int p1 = (t + 64 <= T - 1) ? (t + 64) : (T - 1);

    for (int p = p0; p <= p1; p++) {
        float s = 0.f;
#pragma unroll
        for (int d = 0; d < 16; d++) s += q[d] * bfu(s_kT[d][p]);

        float mn = fmaxf(m, s);
        float em = __expf(m - mn);
        float es = __expf(s - mn);
        l = l * em + es;
#pragma unroll
        for (int d = 0; d < 16; d++)
            oa[d] = oa[d] * em + es * s_vT[d][p];
        m = mn;
    }
    const float inv = 1.0f / l;
    float* orow = o + ((long)(b * F + f) * T + t) * 64 + h * 16;
#pragma unroll
    for (int d4 = 0; d4 < 4; d4++) {
        float4 ov;
        ov.x = oa[d4*4+0] * inv;
        ov.y = oa[d4*4+1] * inv;
        ov.z = oa[d4*4+2] * inv;
        ov.w = oa[d4*4+3] * inv;
        ((float4*)orow)[d4] = ov;
    }
}

// ---------------------------------------------------------------------------
// Fused o-projection + BN + LeakyReLU + final conv1x1.
// ob, y fp32 [b][f][t][64]; out fp32 [b][64][f][t] (reference layout).
// ---------------------------------------------------------------------------
__global__ __launch_bounds__(256) void oproj_final_k(
    const float* __restrict__ ob, const float* __restrict__ y,
    const float* __restrict__ ow, const float* __restrict__ obias,
    const float* __restrict__ sg, const float* __restrict__ sb,
    const float* __restrict__ sm, const float* __restrict__ sv,
    const float* __restrict__ sw, const float* __restrict__ swb,
    float* __restrict__ out)
{
    constexpr int F = 64, T = 512;
    __shared__ float s_ob[64][65];
    __shared__ float s_y2[64][65];
    __shared__ float s_att[64][65];
    __shared__ float s_sc[128], s_sh[128];

    const int tid = threadIdx.x;
    const int t0 = blockIdx.x * 64;
    const int f = blockIdx.y, b = blockIdx.z;

    if (tid < 128) {
        float sc = sg[tid] * rsqrtf(sv[tid] + 1e-5f);
        s_sc[tid] = sc;
        s_sh[tid] = sb[tid] - sm[tid] * sc;
    }
    __syncthreads();

    for (int i = tid; i < 64 * 64; i += 256) {
        int tt = i >> 6, c = i & 63;
        long gi = (((long)b * F + f) * T + t0 + tt) * 64 + c;
        s_ob[c][tt] = ob[gi];
        float yv = y[gi];
        float xn = yv * s_sc[c] + s_sh[c];
        s_y2[c][tt] = (xn >= 0.f) ? xn : 0.01f * xn;
    }
    __syncthreads();

    const int t  = tid & 63;
    const int wv = tid >> 6;

    float acc[16];
#pragma unroll
    for (int i = 0; i < 16; i++) acc[i] = obias[wv * 16 + i];
    for (int c = 0; c < 64; c++) {
        float v = s_ob[c][t];
#pragma unroll
        for (int i = 0; i < 16; i++)
            acc[i] += ow[(wv * 16 + i) * 64 + c] * v;
    }
#pragma unroll
    for (int i = 0; i < 16; i++) {
        int oc = wv * 16 + i;
        float xn = acc[i] * s_sc[64 + oc] + s_sh[64 + oc];
        s_att[oc][t] = (xn >= 0.f) ? xn : 0.01f * xn;
    }
    __syncthreads();

    float acc2[16];
#pragma unroll
    for (int i = 0; i < 16; i++) acc2[i] = swb[wv * 16 + i];
    for (int c = 0; c < 64; c++) {
        float v0 = s_y2[c][t];
        float v1 = s_att[c][t];
#pragma unroll
        for (int i = 0; i < 16; i++) {
            const float* wr = &sw[(wv * 16 + i) * 128];
            acc2[i] += wr[c] * v0 + wr[64 + c] * v1;
        }
    }
#pragma unroll
    for (int i = 0; i < 16; i++)
        out[(((long)b * 64 + wv * 16 + i) * F + f) * T + t0 + t] = acc2[i];
}

// ---------------------------------------------------------------------------
extern "C" void kernel_launch(void* const* d_in, const int* in_sizes, int n_in,
                              void* d_out, int out_size, void* d_ws, size_t ws_size,
                              hipStream_t stream)
{
    (void)in_sizes; (void)n_in; (void)out_size; (void)ws_size;

    const float* x      = (const float*)d_in[0];
    const float* bd0_g  = (const float*)d_in[1];
    const float* bd0_b  = (const float*)d_in[2];
    const float* bd0_m  = (const float*)d_in[3];
    const float* bd0_v  = (const float*)d_in[4];
    const float* bd0_w  = (const float*)d_in[5];
    const float* bd0_wb = (const float*)d_in[6];
    const float* bd1_g  = (const float*)d_in[7];
    const float* bd1_b  = (const float*)d_in[8];
    const float* bd1_m  = (const float*)d_in[9];
    const float* bd1_v  = (const float*)d_in[10];
    const float* bd1_w  = (const float*)d_in[11];
    const float* bd1_wb = (const float*)d_in[12];
    const float* bdo_g  = (const float*)d_in[13];
    const float* bdo_b  = (const float*)d_in[14];
    const float* bdo_m  = (const float*)d_in[15];
    const float* bdo_v  = (const float*)d_in[16];
    const float* bdo_w  = (const float*)d_in[17];
    const float* bdo_wb = (const float*)d_in[18];
    const float* qkv_w  = (const float*)d_in[19];
    const float* qkv_b  = (const float*)d_in[20];
    const float* o_w    = (const float*)d_in[21];
    const float* o_b    = (const float*)d_in[22];
    const float* sao_g  = (const float*)d_in[23];
    const float* sao_b  = (const float*)d_in[24];
    const float* sao_m  = (const float*)d_in[25];
    const float* sao_v  = (const float*)d_in[26];
    const float* sao_w  = (const float*)d_in[27];
    const float* sao_wb = (const float*)d_in[28];

    char* ws = (char*)d_ws;
    // layout (bytes), peak 67.35MB (ws >= 84MB proven):
    //   [0, 16.8M)      x_t bf16 [b][f][t][64]   (reused by ob later)
    //   [16.8, 25.2M)   a0  bf16 [b][f][t][32]
    //   [25.2, 33.6M)   a1  bf16 [b][f][t][32]
    //   [33.6, 67.1M)   y   fp32 [b][f][t][64]
    //   [67.1, 67.35M)  wpack bf16
    u16t*  xt  = (u16t*)(ws);
    u16t*  a0  = (u16t*)(ws + 16777216);
    u16t*  a1  = (u16t*)(ws + 25165824);
    float* y   = (float*)(ws + 33554432);
    u16t*  wpk = (u16t*)(ws + 67108864);
    float* obf = (float*)(ws);             // over xt/a0/a1 (dead after conv2)

    dim3 blk(256);
    dim3 gconv(8, 64, 4);   // T/64, F, B

    hipLaunchKernelGGL(prep_x_k, gconv, blk, 0, stream, x, xt);
    hipLaunchKernelGGL(prep_w_k, dim3(468), blk, 0, stream,
        bd0_w, bd1_w, bdo_w, wpk);
    hipLaunchKernelGGL((conv3x3_mfma_k<64, 32, true>), gconv, blk, 0, stream,
        xt, nullptr, nullptr, bd0_g, bd0_b, bd0_m, bd0_v, wpk, bd0_wb, (void*)a0);
    hipLaunchKernelGGL((conv3x3_mfma_k<96, 32, true>), gconv, blk, 0, stream,
        xt, a0, nullptr, bd1_g, bd1_b, bd1_m, bd1_v, wpk + 18432, bd1_wb, (void*)a1);
    hipLaunchKernelGGL((conv3x3_mfma_k<128, 64, false>), gconv, blk, 0, stream,
        xt, a0, a1, bdo_g, bdo_b, bdo_m, bdo_v, wpk + 46080, bdo_wb, (void*)y);
    hipLaunchKernelGGL(attn_fused_k, dim3(4, 64, 4), dim3(512), 0, stream,
        y, qkv_w, qkv_b, obf);
    hipLaunchKernelGGL(oproj_final_k, gconv, blk, 0, stream,
        obf, y, o_w, o_b, sao_g, sao_b, sao_m, sao_v, sao_w, sao_wb,
        (float*)d_out);
}

// Round 7
// 445.311 us; speedup vs baseline: 2.8826x; 1.3734x over previous
//
#include <hip/hip_runtime.h>
#include <hip/hip_bf16.h>

typedef unsigned short u16t;
typedef __attribute__((ext_vector_type(8))) short bfrag;      // 8 bf16 bits
typedef __attribute__((ext_vector_type(4))) float f32x4;      // MFMA acc
typedef __attribute__((ext_vector_type(8))) unsigned short uh8;

__device__ __forceinline__ float bfu(u16t u) {
    union { unsigned int i; float f; } c;
    c.i = ((unsigned int)u) << 16;
    return c.f;
}
__device__ __forceinline__ u16t fbf(float f) {
    __hip_bfloat16 h = __float2bfloat16(f);
    return *reinterpret_cast<u16t*>(&h);
}

// ---------------------------------------------------------------------------
// x [b][64c][64f][512t] fp32  ->  x_t [b][f][t][64c] bf16
// ---------------------------------------------------------------------------
__global__ __launch_bounds__(256) void prep_x_k(
    const float* __restrict__ x, u16t* __restrict__ xt)
{
    constexpr int F = 64, T = 512;
    __shared__ u16t su[64][74];
    const int tid = threadIdx.x;
    const int t0 = blockIdx.x * 64;
    const int f = blockIdx.y, b = blockIdx.z;

#pragma unroll
    for (int p = 0; p < 16; p++) {
        int i = tid + 256 * p;
        int c = i >> 6, t = i & 63;
        su[c][t] = fbf(x[(((long)b * 64 + c) * F + f) * T + t0 + t]);
    }
    __syncthreads();
#pragma unroll
    for (int p = 0; p < 2; p++) {
        int i = tid + 256 * p;
        int t = i >> 3, c8 = i & 7;
        uh8 v;
#pragma unroll
        for (int j = 0; j < 8; j++) v[j] = su[c8 * 8 + j][t];
        *(uh8*)&xt[(((long)b * F + f) * T + t0 + t) * 64 + c8 * 8] = v;
    }
}

// ---------------------------------------------------------------------------
// Pack weights fp32 -> bf16 A-fragments [kblock][co][32].
// conv0 @0 (18432) | conv1 @18432 (27648) | conv2 @46080 (73728)
// o_w @119808 (4096) | sao_w @123904 (8192)   total 132096
// ---------------------------------------------------------------------------
__global__ __launch_bounds__(256) void prep_w_k(
    const float* __restrict__ w0, const float* __restrict__ w1,
    const float* __restrict__ w2, const float* __restrict__ ow,
    const float* __restrict__ sw, u16t* __restrict__ wp)
{
    int idx = blockIdx.x * 256 + threadIdx.x;
    if (idx >= 132096) return;
    if (idx < 119808) {
        int C_IN, C_OUT, e;
        const float* src;
        if (idx < 18432)      { C_IN = 64;  C_OUT = 32; src = w0; e = idx; }
        else if (idx < 46080) { C_IN = 96;  C_OUT = 32; src = w1; e = idx - 18432; }
        else                  { C_IN = 128; C_OUT = 64; src = w2; e = idx - 46080; }
        int NCB = C_IN / 32;
        int ks = e & 31;
        int e2 = e >> 5;
        int co = e2 % C_OUT;
        int e3 = e2 / C_OUT;
        int cb = e3 % NCB;
        int kk = e3 / NCB;
        int c  = cb * 32 + ks;
        int kh = kk / 3, kw = kk % 3;
        wp[idx] = fbf(src[((co * C_IN + c) * 3 + kh) * 3 + kw]);
    } else if (idx < 123904) {
        int e = idx - 119808;
        int ks = e & 31, co = (e >> 5) & 63, kb = e >> 11;   // kb 0..1
        wp[idx] = fbf(ow[co * 64 + kb * 32 + ks]);
    } else {
        int e = idx - 123904;
        int ks = e & 31, co = (e >> 5) & 63, kb = e >> 11;   // kb 0..3
        wp[idx] = fbf(sw[co * 128 + kb * 32 + ks]);
    }
}

// ---------------------------------------------------------------------------
// MFMA fused BN + LeakyReLU + 3x3 conv (proven round 6).
// ---------------------------------------------------------------------------
template<int C_IN, int C_OUT, bool OBF>
__global__ __launch_bounds__(256) void conv3x3_mfma_k(
    const u16t* __restrict__ s0, const u16t* __restrict__ s1,
    const u16t* __restrict__ s2,
    const float* __restrict__ gg, const float* __restrict__ bb,
    const float* __restrict__ mm, const float* __restrict__ vv,
    const u16t* __restrict__ wseg, const float* __restrict__ wb,
    void* __restrict__ dstv)
{
    constexpr int F = 64, T = 512, TT = 64;
    constexpr int CP = C_IN + 8;
    constexpr int NCB = C_IN / 32;
    constexpr int NCOT = C_OUT / 16;
    constexpr int CS = C_IN / 8;
    constexpr int CSP = (CS <= 8) ? 8 : 16;
    constexpr int RPP = 256 / CSP;
    constexpr int NPASS = (198 + RPP - 1) / RPP;

    __shared__ __align__(16) u16t s_x[3][66][CP];

    const int tid = threadIdx.x;
    const int t0 = blockIdx.x * TT;
    const int f  = blockIdx.y;
    const int b  = blockIdx.z;

    const int c8 = tid % CSP;
    const int r0 = tid / CSP;
    const bool cok = (c8 < CS);

    float sc[8], sh[8];
    if (cok) {
#pragma unroll
        for (int j = 0; j < 8; j++) {
            int c = c8 * 8 + j;
            float s = gg[c] * rsqrtf(vv[c] + 1e-5f);
            sc[j] = s;
            sh[j] = bb[c] - mm[c] * s;
        }
    }

    for (int p = 0; p < NPASS; p++) {
        int row = r0 + p * RPP;
        if (row < 198 && cok) {
            int kh = (row >= 132) ? 2 : ((row >= 66) ? 1 : 0);
            int tp = row - kh * 66;
            int fi = f + kh - 1;
            int tg = t0 + tp - 1;
            uh8 v = (uh8)0;
            if ((unsigned)fi < (unsigned)F && (unsigned)tg < (unsigned)T) {
                const u16t* sp; int coff, cw;
                if (c8 < 8)       { sp = s0; coff = c8 * 8;        cw = 64; }
                else if (c8 < 12) { sp = s1; coff = (c8 - 8) * 8;  cw = 32; }
                else              { sp = s2; coff = (c8 - 12) * 8; cw = 32; }
                uh8 raw = *(const uh8*)&sp[(((long)b * F + fi) * T + tg) * cw + coff];
#pragma unroll
                for (int j = 0; j < 8; j++) {
                    float xv = bfu(raw[j]);
                    float xn = fmaf(xv, sc[j], sh[j]);
                    v[j] = fbf(fmaxf(xn, 0.01f * xn));
                }
            }
            *(uh8*)&s_x[kh][tp][c8 * 8] = v;
        }
    }
    __syncthreads();

    const int l  = tid & 63;
    const int wv = tid >> 6;
    const int lr = l & 15;
    const int lq = l >> 4;

    f32x4 acc[NCOT];
#pragma unroll
    for (int i = 0; i < NCOT; i++) acc[i] = (f32x4){0.f, 0.f, 0.f, 0.f};

    const int tbase = wv * 16 + lr;
    const int cbase = lq * 8;
    const int aoff  = lr * 32 + lq * 8;

    int it = 0;
#pragma unroll
    for (int kh = 0; kh < 3; kh++)
#pragma unroll
    for (int kw = 0; kw < 3; kw++)
#pragma unroll
    for (int cb = 0; cb < NCB; cb++) {
        bfrag B = *(const bfrag*)&s_x[kh][tbase + kw][cb * 32 + cbase];
#pragma unroll
        for (int ct = 0; ct < NCOT; ct++) {
            bfrag A = *(const bfrag*)&wseg[(it * C_OUT + ct * 16) * 32 + aoff];
            acc[ct] = __builtin_amdgcn_mfma_f32_16x16x32_bf16(A, B, acc[ct], 0, 0, 0);
        }
        it++;
    }

    const int t = t0 + wv * 16 + lr;
#pragma unroll
    for (int ct = 0; ct < NCOT; ct++) {
        int co0 = ct * 16 + lq * 4;
        float4 bs = *(const float4*)&wb[co0];
        long obase = (((long)b * F + f) * T + t) * C_OUT + co0;
        if (OBF) {
            u16t* dp = (u16t*)dstv;
            ushort4 pk;
            pk.x = fbf(acc[ct][0] + bs.x);
            pk.y = fbf(acc[ct][1] + bs.y);
            pk.z = fbf(acc[ct][2] + bs.z);
            pk.w = fbf(acc[ct][3] + bs.w);
            *(ushort4*)&dp[obase] = pk;
        } else {
            float* dp = (float*)dstv;
            float4 ov;
            ov.x = acc[ct][0] + bs.x;
            ov.y = acc[ct][1] + bs.y;
            ov.z = acc[ct][2] + bs.z;
            ov.w = acc[ct][3] + bs.w;
            *(float4*)&dp[obase] = ov;
        }
    }
}

// ---------------------------------------------------------------------------
// Fused qkv-projection + banded local attention.  y fp32 [b][f][t][64].
// K and V bf16 LDS [d][t] (stride-1 lane reads, ~46KB -> 3 blocks/CU).
// Phantom zero-keys for t<64: init m=0, l=64-t.  ob out bf16 [b][f][t][64].
// ---------------------------------------------------------------------------
__global__ __launch_bounds__(512) void attn_fused_k(
    const float* __restrict__ y, const float* __restrict__ qw,
    const float* __restrict__ qb, u16t* __restrict__ o)
{
    constexpr int F = 64, T = 512;
    const int h = blockIdx.x, f = blockIdx.y, b = blockIdx.z;
    const int t = threadIdx.x;

    __shared__ float s_wT[64][48];
    __shared__ float s_b[48];
    __shared__ u16t  s_kT[16][T + 8];
    __shared__ u16t  s_vT[16][T + 8];

    for (int i = t; i < 64 * 48; i += 512) {
        int c = i / 48, r = i - c * 48;
        int kind = r >> 4, d = r & 15;
        s_wT[c][r] = qw[(kind * 64 + h * 16 + d) * 64 + c];
    }
    if (t < 48) {
        int kind = t >> 4, d = t & 15;
        s_b[t] = qb[kind * 64 + h * 16 + d];
    }
    __syncthreads();

    float acc[48];
#pragma unroll
    for (int r = 0; r < 48; r++) acc[r] = s_b[r];

    const float* yrow = y + ((long)(b * F + f) * T + t) * 64;
#pragma unroll 4
    for (int c4 = 0; c4 < 16; c4++) {
        float4 y4 = ((const float4*)yrow)[c4];
#pragma unroll
        for (int k = 0; k < 4; k++) {
            float yv = (k == 0) ? y4.x : (k == 1) ? y4.y : (k == 2) ? y4.z : y4.w;
            const float4* wrow = (const float4*)(&s_wT[c4 * 4 + k][0]);
#pragma unroll
            for (int r4 = 0; r4 < 12; r4++) {
                float4 w4 = wrow[r4];
                acc[r4*4+0] += w4.x * yv;
                acc[r4*4+1] += w4.y * yv;
                acc[r4*4+2] += w4.z * yv;
                acc[r4*4+3] += w4.w * yv;
            }
        }
    }
#pragma unroll
    for (int d = 0; d < 16; d++) {
        s_kT[d][t] = fbf(acc[16 + d]);
        s_vT[d][t] = fbf(acc[32 + d]);
    }
    float q[16];
#pragma unroll
    for (int d = 0; d < 16; d++) q[d] = 0.25f * acc[d];  // fold 1/sqrt(16)
    __syncthreads();

    const int n_neg = (t < 64) ? (64 - t) : 0;
    float m = (n_neg > 0) ? 0.f : -3.0e38f;
    float l = (float)n_neg;
    float oa[16];
#pragma unroll
    for (int d = 0; d < 16; d++) oa[d] = 0.f;

    const int p0 = (t >= 64) ? (t - 64) : 0;
    const int p1 = (t + 64 <= T - 1) ? (t + 64) : (T - 1);

    for (int p = p0; p <= p1; p++) {
        float s = 0.f;
#pragma unroll
        for (int d = 0; d < 16; d++) s += q[d] * bfu(s_kT[d][p]);

        float mn = fmaxf(m, s);
        float em = __expf(m - mn);
        float es = __expf(s - mn);
        l = l * em + es;
#pragma unroll
        for (int d = 0; d < 16; d++)
            oa[d] = oa[d] * em + es * bfu(s_vT[d][p]);
        m = mn;
    }
    const float inv = 1.0f / l;
    u16t* orow = o + ((long)(b * F + f) * T + t) * 64 + h * 16;
#pragma unroll
    for (int d4 = 0; d4 < 4; d4++) {
        ushort4 pk;
        pk.x = fbf(oa[d4*4+0] * inv);
        pk.y = fbf(oa[d4*4+1] * inv);
        pk.z = fbf(oa[d4*4+2] * inv);
        pk.w = fbf(oa[d4*4+3] * inv);
        *(ushort4*)&orow[d4 * 4] = pk;
    }
}

// ---------------------------------------------------------------------------
// MFMA fused o-projection + BN + LeakyReLU + final conv1x1.
// MFMA1: att = ow @ ob (K=64) -> BN+lrelu -> s_att bf16 LDS.
// MFMA2: out = sw @ [y2; att] (K=128), y2 = bn_lrelu(y) staged on the fly.
// out fp32 [b][64][f][t] (reference layout).
// ---------------------------------------------------------------------------
__global__ __launch_bounds__(256) void final_mfma_k(
    const u16t* __restrict__ ob, const float* __restrict__ y,
    const u16t* __restrict__ wo, const float* __restrict__ obias,
    const float* __restrict__ sg, const float* __restrict__ sb,
    const float* __restrict__ sm, const float* __restrict__ sv,
    const u16t* __restrict__ wsao, const float* __restrict__ swb,
    float* __restrict__ out)
{
    constexpr int F = 64, T = 512, TT = 64, P = 72;
    __shared__ __align__(16) u16t s_ob[64][P];
    __shared__ __align__(16) u16t s_y2[64][P];
    __shared__ __align__(16) u16t s_att[64][P];
    __shared__ float s_sc[128], s_sh[128];

    const int tid = threadIdx.x;
    const int t0 = blockIdx.x * TT;
    const int f = blockIdx.y, b = blockIdx.z;

    if (tid < 128) {
        float sc = sg[tid] * rsqrtf(sv[tid] + 1e-5f);
        s_sc[tid] = sc;
        s_sh[tid] = sb[tid] - sm[tid] * sc;
    }
    __syncthreads();

    // stage ob (bf16 direct) and y2 = lrelu(y*sc+sh) (fp32 -> bf16)
    for (int i = tid; i < 512; i += 256) {
        int tt = i >> 3, c0 = (i & 7) * 8;
        long gi = (((long)b * F + f) * T + t0 + tt) * 64 + c0;
        *(uh8*)&s_ob[tt][c0] = *(const uh8*)&ob[gi];
        float4 ya = *(const float4*)&y[gi];
        float4 yb = *(const float4*)&y[gi + 4];
        float yv[8] = {ya.x, ya.y, ya.z, ya.w, yb.x, yb.y, yb.z, yb.w};
        uh8 v;
#pragma unroll
        for (int j = 0; j < 8; j++) {
            float xn = fmaf(yv[j], s_sc[c0 + j], s_sh[c0 + j]);
            v[j] = fbf(fmaxf(xn, 0.01f * xn));
        }
        *(uh8*)&s_y2[tt][c0] = v;
    }
    __syncthreads();

    const int l  = tid & 63;
    const int wv = tid >> 6;
    const int lr = l & 15;
    const int lq = l >> 4;
    const int tbase = wv * 16 + lr;
    const int cbase = lq * 8;

    // MFMA1: o-projection, K=64
    f32x4 acc1[4];
#pragma unroll
    for (int i = 0; i < 4; i++) acc1[i] = (f32x4){0.f, 0.f, 0.f, 0.f};
#pragma unroll
    for (int kb = 0; kb < 2; kb++) {
        bfrag B = *(const bfrag*)&s_ob[tbase][kb * 32 + cbase];
#pragma unroll
        for (int ct = 0; ct < 4; ct++) {
            bfrag A = *(const bfrag*)&wo[(kb * 64 + ct * 16 + lr) * 32 + lq * 8];
            acc1[ct] = __builtin_amdgcn_mfma_f32_16x16x32_bf16(A, B, acc1[ct], 0, 0, 0);
        }
    }
    // epilogue: +obias, BN(ch 64..127), lrelu -> s_att[t][co]
#pragma unroll
    for (int ct = 0; ct < 4; ct++) {
        int co = ct * 16 + lq * 4;
        float4 bi = *(const float4*)&obias[co];
#pragma unroll
        for (int j = 0; j < 4; j++) {
            float a = acc1[ct][j] + ((j == 0) ? bi.x : (j == 1) ? bi.y : (j == 2) ? bi.z : bi.w);
            int cg = 64 + co + j;
            float xn = fmaf(a, s_sc[cg], s_sh[cg]);
            s_att[tbase][co + j] = fbf(fmaxf(xn, 0.01f * xn));
        }
    }
    __syncthreads();

    // MFMA2: final conv1x1, K=128 over [y2 | att]
    f32x4 acc2[4];
#pragma unroll
    for (int i = 0; i < 4; i++) acc2[i] = (f32x4){0.f, 0.f, 0.f, 0.f};
#pragma unroll
    for (int kb = 0; kb < 4; kb++) {
        bfrag B = (kb < 2) ? *(const bfrag*)&s_y2[tbase][kb * 32 + cbase]
                           : *(const bfrag*)&s_att[tbase][(kb - 2) * 32 + cbase];
#pragma unroll
        for (int ct = 0; ct < 4; ct++) {
            bfrag A = *(const bfrag*)&wsao[(kb * 64 + ct * 16 + lr) * 32 + lq * 8];
            acc2[ct] = __builtin_amdgcn_mfma_f32_16x16x32_bf16(A, B, acc2[ct], 0, 0, 0);
        }
    }
    const int t = t0 + wv * 16 + lr;
#pragma unroll
    for (int ct = 0; ct < 4; ct++) {
        int co0 = ct * 16 + lq * 4;
        float4 bs = *(const float4*)&swb[co0];
#pragma unroll
        for (int j = 0; j < 4; j++) {
            float bv = (j == 0) ? bs.x : (j == 1) ? bs.y : (j == 2) ? bs.z : bs.w;
            out[(((long)b * 64 + co0 + j) * F + f) * T + t] = acc2[ct][j] + bv;
        }
    }
}

// ---------------------------------------------------------------------------
extern "C" void kernel_launch(void* const* d_in, const int* in_sizes, int n_in,
                              void* d_out, int out_size, void* d_ws, size_t ws_size,
                              hipStream_t stream)
{
    (void)in_sizes; (void)n_in; (void)out_size; (void)ws_size;

    const float* x      = (const float*)d_in[0];
    const float* bd0_g  = (const float*)d_in[1];
    const float* bd0_b  = (const float*)d_in[2];
    const float* bd0_m  = (const float*)d_in[3];
    const float* bd0_v  = (const float*)d_in[4];
    const float* bd0_w  = (const float*)d_in[5];
    const float* bd0_wb = (const float*)d_in[6];
    const float* bd1_g  = (const float*)d_in[7];
    const float* bd1_b  = (const float*)d_in[8];
    const float* bd1_m  = (const float*)d_in[9];
    const float* bd1_v  = (const float*)d_in[10];
    const float* bd1_w  = (const float*)d_in[11];
    const float* bd1_wb = (const float*)d_in[12];
    const float* bdo_g  = (const float*)d_in[13];
    const float* bdo_b  = (const float*)d_in[14];
    const float* bdo_m  = (const float*)d_in[15];
    const float* bdo_v  = (const float*)d_in[16];
    const float* bdo_w  = (const float*)d_in[17];
    const float* bdo_wb = (const float*)d_in[18];
    const float* qkv_w  = (const float*)d_in[19];
    const float* qkv_b  = (const float*)d_in[20];
    const float* o_w    = (const float*)d_in[21];
    const float* o_b    = (const float*)d_in[22];
    const float* sao_g  = (const float*)d_in[23];
    const float* sao_b  = (const float*)d_in[24];
    const float* sao_m  = (const float*)d_in[25];
    const float* sao_v  = (const float*)d_in[26];
    const float* sao_w  = (const float*)d_in[27];
    const float* sao_wb = (const float*)d_in[28];

    char* ws = (char*)d_ws;
    // layout (bytes), peak 67.4MB (ws >= 83.9MB proven):
    //   [0, 16.8M)      x_t bf16 [b][f][t][64]  (ob bf16 reuses [0,8.4M) later)
    //   [16.8, 25.2M)   a0  bf16 [b][f][t][32]
    //   [25.2, 33.6M)   a1  bf16 [b][f][t][32]
    //   [33.6, 67.1M)   y   fp32 [b][f][t][64]
    //   [67.1, 67.4M)   wpack bf16 (132096 entries)
    u16t*  xt  = (u16t*)(ws);
    u16t*  a0  = (u16t*)(ws + 16777216);
    u16t*  a1  = (u16t*)(ws + 25165824);
    float* y   = (float*)(ws + 33554432);
    u16t*  wpk = (u16t*)(ws + 67108864);
    u16t*  obf = (u16t*)(ws);              // bf16, over xt (dead after conv2)

    dim3 blk(256);
    dim3 gconv(8, 64, 4);   // T/64, F, B

    hipLaunchKernelGGL(prep_x_k, gconv, blk, 0, stream, x, xt);
    hipLaunchKernelGGL(prep_w_k, dim3(516), blk, 0, stream,
        bd0_w, bd1_w, bdo_w, o_w, sao_w, wpk);
    hipLaunchKernelGGL((conv3x3_mfma_k<64, 32, true>), gconv, blk, 0, stream,
        xt, nullptr, nullptr, bd0_g, bd0_b, bd0_m, bd0_v, wpk, bd0_wb, (void*)a0);
    hipLaunchKernelGGL((conv3x3_mfma_k<96, 32, true>), gconv, blk, 0, stream,
        xt, a0, nullptr, bd1_g, bd1_b, bd1_m, bd1_v, wpk + 18432, bd1_wb, (void*)a1);
    hipLaunchKernelGGL((conv3x3_mfma_k<128, 64, false>), gconv, blk, 0, stream,
        xt, a0, a1, bdo_g, bdo_b, bdo_m, bdo_v, wpk + 46080, bdo_wb, (void*)y);
    hipLaunchKernelGGL(attn_fused_k, dim3(4, 64, 4), dim3(512), 0, stream,
        y, qkv_w, qkv_b, obf);
    hipLaunchKernelGGL(final_mfma_k, gconv, blk, 0, stream,
        obf, y, wpk + 119808, o_b, sao_g, sao_b, sao_m, sao_v,
        wpk + 123904, sao_wb, (float*)d_out);
}

// Round 9
// 258.402 us; speedup vs baseline: 4.9677x; 1.7233x over previous
//
#include <hip/hip_runtime.h>
#include <hip/hip_bf16.h>

typedef unsigned short u16t;
typedef __attribute__((ext_vector_type(8))) short bfrag;      // 8 bf16 bits
typedef __attribute__((ext_vector_type(4))) float f32x4;      // MFMA acc
typedef __attribute__((ext_vector_type(8))) unsigned short uh8;

__device__ __forceinline__ float bfu(u16t u) {
    union { unsigned int i; float f; } c;
    c.i = ((unsigned int)u) << 16;
    return c.f;
}
__device__ __forceinline__ u16t fbf(float f) {
    __hip_bfloat16 h = __float2bfloat16(f);
    return *reinterpret_cast<u16t*>(&h);
}

// ---------------------------------------------------------------------------
// x [b][64c][64f][512t] fp32  ->  x_t [b][f][t][64c] bf16
// ---------------------------------------------------------------------------
__global__ __launch_bounds__(256) void prep_x_k(
    const float* __restrict__ x, u16t* __restrict__ xt)
{
    constexpr int F = 64, T = 512;
    __shared__ u16t su[64][74];
    const int tid = threadIdx.x;
    const int t0 = blockIdx.x * 64;
    const int f = blockIdx.y, b = blockIdx.z;

#pragma unroll
    for (int p = 0; p < 16; p++) {
        int i = tid + 256 * p;
        int c = i >> 6, t = i & 63;
        su[c][t] = fbf(x[(((long)b * 64 + c) * F + f) * T + t0 + t]);
    }
    __syncthreads();
#pragma unroll
    for (int p = 0; p < 2; p++) {
        int i = tid + 256 * p;
        int t = i >> 3, c8 = i & 7;
        uh8 v;
#pragma unroll
        for (int j = 0; j < 8; j++) v[j] = su[c8 * 8 + j][t];
        *(uh8*)&xt[(((long)b * F + f) * T + t0 + t) * 64 + c8 * 8] = v;
    }
}

// ---------------------------------------------------------------------------
// Pack weights fp32 -> bf16 A-fragments [kblock][co][32].
// conv0 @0 | conv1 @18432 | conv2 @46080 | o_w @119808 | sao_w @123904 |
// qkv_w @132096 (12288)   total 144384
// ---------------------------------------------------------------------------
__global__ __launch_bounds__(256) void prep_w_k(
    const float* __restrict__ w0, const float* __restrict__ w1,
    const float* __restrict__ w2, const float* __restrict__ ow,
    const float* __restrict__ sw, const float* __restrict__ qw,
    u16t* __restrict__ wp)
{
    int idx = blockIdx.x * 256 + threadIdx.x;
    if (idx >= 144384) return;
    if (idx < 119808) {
        int C_IN, C_OUT, e;
        const float* src;
        if (idx < 18432)      { C_IN = 64;  C_OUT = 32; src = w0; e = idx; }
        else if (idx < 46080) { C_IN = 96;  C_OUT = 32; src = w1; e = idx - 18432; }
        else                  { C_IN = 128; C_OUT = 64; src = w2; e = idx - 46080; }
        int NCB = C_IN / 32;
        int ks = e & 31;
        int e2 = e >> 5;
        int co = e2 % C_OUT;
        int e3 = e2 / C_OUT;
        int cb = e3 % NCB;
        int kk = e3 / NCB;
        int c  = cb * 32 + ks;
        int kh = kk / 3, kw = kk % 3;
        wp[idx] = fbf(src[((co * C_IN + c) * 3 + kh) * 3 + kw]);
    } else if (idx < 123904) {
        int e = idx - 119808;
        int ks = e & 31, co = (e >> 5) & 63, kb = e >> 11;
        wp[idx] = fbf(ow[co * 64 + kb * 32 + ks]);
    } else if (idx < 132096) {
        int e = idx - 123904;
        int ks = e & 31, co = (e >> 5) & 63, kb = e >> 11;
        wp[idx] = fbf(sw[co * 128 + kb * 32 + ks]);
    } else {
        int e = idx - 132096;
        int ks = e & 31, co = (e >> 5) % 192, kb = e / 6144;
        wp[idx] = fbf(qw[co * 64 + kb * 32 + ks]);
    }
}

// ---------------------------------------------------------------------------
// MFMA fused BN + LeakyReLU + 3x3 conv (proven rounds 6/7).
// ---------------------------------------------------------------------------
template<int C_IN, int C_OUT, bool OBF>
__global__ __launch_bounds__(256) void conv3x3_mfma_k(
    const u16t* __restrict__ s0, const u16t* __restrict__ s1,
    const u16t* __restrict__ s2,
    const float* __restrict__ gg, const float* __restrict__ bb,
    const float* __restrict__ mm, const float* __restrict__ vv,
    const u16t* __restrict__ wseg, const float* __restrict__ wb,
    void* __restrict__ dstv)
{
    constexpr int F = 64, T = 512, TT = 64;
    constexpr int CP = C_IN + 8;
    constexpr int NCB = C_IN / 32;
    constexpr int NCOT = C_OUT / 16;
    constexpr int CS = C_IN / 8;
    constexpr int CSP = (CS <= 8) ? 8 : 16;
    constexpr int RPP = 256 / CSP;
    constexpr int NPASS = (198 + RPP - 1) / RPP;

    __shared__ __align__(16) u16t s_x[3][66][CP];

    const int tid = threadIdx.x;
    const int t0 = blockIdx.x * TT;
    const int f  = blockIdx.y;
    const int b  = blockIdx.z;

    const int c8 = tid % CSP;
    const int r0 = tid / CSP;
    const bool cok = (c8 < CS);

    float sc[8], sh[8];
    if (cok) {
#pragma unroll
        for (int j = 0; j < 8; j++) {
            int c = c8 * 8 + j;
            float s = gg[c] * rsqrtf(vv[c] + 1e-5f);
            sc[j] = s;
            sh[j] = bb[c] - mm[c] * s;
        }
    }

    for (int p = 0; p < NPASS; p++) {
        int row = r0 + p * RPP;
        if (row < 198 && cok) {
            int kh = (row >= 132) ? 2 : ((row >= 66) ? 1 : 0);
            int tp = row - kh * 66;
            int fi = f + kh - 1;
            int tg = t0 + tp - 1;
            uh8 v = (uh8)0;
            if ((unsigned)fi < (unsigned)F && (unsigned)tg < (unsigned)T) {
                const u16t* sp; int coff, cw;
                if (c8 < 8)       { sp = s0; coff = c8 * 8;        cw = 64; }
                else if (c8 < 12) { sp = s1; coff = (c8 - 8) * 8;  cw = 32; }
                else              { sp = s2; coff = (c8 - 12) * 8; cw = 32; }
                uh8 raw = *(const uh8*)&sp[(((long)b * F + fi) * T + tg) * cw + coff];
#pragma unroll
                for (int j = 0; j < 8; j++) {
                    float xv = bfu(raw[j]);
                    float xn = fmaf(xv, sc[j], sh[j]);
                    v[j] = fbf(fmaxf(xn, 0.01f * xn));
                }
            }
            *(uh8*)&s_x[kh][tp][c8 * 8] = v;
        }
    }
    __syncthreads();

    const int l  = tid & 63;
    const int wv = tid >> 6;
    const int lr = l & 15;
    const int lq = l >> 4;

    f32x4 acc[NCOT];
#pragma unroll
    for (int i = 0; i < NCOT; i++) acc[i] = (f32x4){0.f, 0.f, 0.f, 0.f};

    const int tbase = wv * 16 + lr;
    const int cbase = lq * 8;
    const int aoff  = lr * 32 + lq * 8;

    int it = 0;
#pragma unroll
    for (int kh = 0; kh < 3; kh++)
#pragma unroll
    for (int kw = 0; kw < 3; kw++)
#pragma unroll
    for (int cb = 0; cb < NCB; cb++) {
        bfrag B = *(const bfrag*)&s_x[kh][tbase + kw][cb * 32 + cbase];
#pragma unroll
        for (int ct = 0; ct < NCOT; ct++) {
            bfrag A = *(const bfrag*)&wseg[(it * C_OUT + ct * 16) * 32 + aoff];
            acc[ct] = __builtin_amdgcn_mfma_f32_16x16x32_bf16(A, B, acc[ct], 0, 0, 0);
        }
        it++;
    }

    const int t = t0 + wv * 16 + lr;
#pragma unroll
    for (int ct = 0; ct < NCOT; ct++) {
        int co0 = ct * 16 + lq * 4;
        float4 bs = *(const float4*)&wb[co0];
        long obase = (((long)b * F + f) * T + t) * C_OUT + co0;
        if (OBF) {
            u16t* dp = (u16t*)dstv;
            ushort4 pk;
            pk.x = fbf(acc[ct][0] + bs.x);
            pk.y = fbf(acc[ct][1] + bs.y);
            pk.z = fbf(acc[ct][2] + bs.z);
            pk.w = fbf(acc[ct][3] + bs.w);
            *(ushort4*)&dp[obase] = pk;
        } else {
            float* dp = (float*)dstv;
            float4 ov;
            ov.x = acc[ct][0] + bs.x;
            ov.y = acc[ct][1] + bs.y;
            ov.z = acc[ct][2] + bs.z;
            ov.w = acc[ct][3] + bs.w;
            *(float4*)&dp[obase] = ov;
        }
    }
}

// ---------------------------------------------------------------------------
// MFMA qkv projection.  ybf bf16 [b][f][t][64] -> Q [b][f][t][64] (x0.25),
// K [b][f][h][t][16], V^T [b][f][h][d][t]   (all bf16).
// ---------------------------------------------------------------------------
__global__ __launch_bounds__(256) void qkv_mfma_k(
    const u16t* __restrict__ ybf, const u16t* __restrict__ wq,
    const float* __restrict__ qbias,
    u16t* __restrict__ q_t, u16t* __restrict__ k_t, u16t* __restrict__ v_t)
{
    constexpr int F = 64, T = 512;
    __shared__ __align__(16) u16t s_y[64][72];
    const int tid = threadIdx.x;
    const int t0 = blockIdx.x * 64;
    const int f = blockIdx.y, b = blockIdx.z;
    const long bf = (long)b * F + f;

    for (int i = tid; i < 512; i += 256) {
        int tt = i >> 3, c0 = (i & 7) * 8;
        *(uh8*)&s_y[tt][c0] = *(const uh8*)&ybf[(bf * T + t0 + tt) * 64 + c0];
    }
    __syncthreads();

    const int l = tid & 63, wv = tid >> 6;
    const int lr = l & 15, lq = l >> 4;
    const int tb = wv * 16 + lr;

    bfrag B0 = *(const bfrag*)&s_y[tb][lq * 8];
    bfrag B1 = *(const bfrag*)&s_y[tb][32 + lq * 8];

    f32x4 acc[12];
#pragma unroll
    for (int i = 0; i < 12; i++) acc[i] = (f32x4){0.f, 0.f, 0.f, 0.f};
#pragma unroll
    for (int ct = 0; ct < 12; ct++) {
        bfrag A0 = *(const bfrag*)&wq[(ct * 16 + lr) * 32 + lq * 8];
        acc[ct] = __builtin_amdgcn_mfma_f32_16x16x32_bf16(A0, B0, acc[ct], 0, 0, 0);
    }
#pragma unroll
    for (int ct = 0; ct < 12; ct++) {
        bfrag A1 = *(const bfrag*)&wq[(192 + ct * 16 + lr) * 32 + lq * 8];
        acc[ct] = __builtin_amdgcn_mfma_f32_16x16x32_bf16(A1, B1, acc[ct], 0, 0, 0);
    }

    const int t = t0 + tb;
#pragma unroll
    for (int ct = 0; ct < 12; ct++) {
        int co0 = ct * 16 + lq * 4;
        float4 bi = *(const float4*)&qbias[co0];
        float a0 = acc[ct][0] + bi.x, a1 = acc[ct][1] + bi.y;
        float a2 = acc[ct][2] + bi.z, a3 = acc[ct][3] + bi.w;
        if (co0 < 64) {
            ushort4 pk;
            pk.x = fbf(a0 * 0.25f); pk.y = fbf(a1 * 0.25f);
            pk.z = fbf(a2 * 0.25f); pk.w = fbf(a3 * 0.25f);
            *(ushort4*)&q_t[(bf * T + t) * 64 + co0] = pk;
        } else if (co0 < 128) {
            int hh = (co0 - 64) >> 4, d0 = (co0 - 64) & 15;
            ushort4 pk;
            pk.x = fbf(a0); pk.y = fbf(a1); pk.z = fbf(a2); pk.w = fbf(a3);
            *(ushort4*)&k_t[((bf * 4 + hh) * T + t) * 16 + d0] = pk;
        } else {
            int hh = (co0 - 128) >> 4, d0 = (co0 - 128) & 15;
            long vb = (bf * 4 + hh) * 16;
            v_t[(vb + d0 + 0) * T + t] = fbf(a0);
            v_t[(vb + d0 + 1) * T + t] = fbf(a1);
            v_t[(vb + d0 + 2) * T + t] = fbf(a2);
            v_t[(vb + d0 + 3) * T + t] = fbf(a3);
        }
    }
}

// ---------------------------------------------------------------------------
// MFMA banded attention.  Block = (h, 64-query chunk, f, b), 4 waves x 16 q.
// Staged keys [qb0-64, qb0+127] (192); zero-staged outside [0,512).
// Mask: include iff 0 <= rk-lr <= 128 and p < 512; phantom p<0 keys give
// raw score 0 via zero-K (matches reference zero-pad).  Full softmax in
// registers (36 scores/lane), butterfly reduce, P bf16 -> LDS, PV MFMA.
// NOTE: ob may alias q_t: each block writes exactly the (t,channel) tile it
// read Q from; store is data-dependent on the load within lockstep waves.
// ---------------------------------------------------------------------------
__global__ __launch_bounds__(256) void attn_mfma_k(
    const u16t* __restrict__ qt, const u16t* __restrict__ kt_,
    const u16t* __restrict__ vt, u16t* __restrict__ ob)
{
    constexpr int T = 512, F = 64;
    const int qc = blockIdx.x & 7;
    const int h  = blockIdx.x >> 3;
    const int f = blockIdx.y, b = blockIdx.z;
    const int qb0 = qc * 64;
    const int tid = threadIdx.x;
    const long bf = (long)b * F + f;
    const long kvb = bf * 4 + h;

    __shared__ __align__(16) u16t s_k[192][24];
    __shared__ __align__(16) u16t s_v[16][216];
    __shared__ __align__(16) u16t s_p[4][16][168];
    __shared__ __align__(16) u16t s_zero[8];

    if (tid < 8) s_zero[tid] = 0;

    for (int idx = tid; idx < 384; idx += 256) {
        int kk = idx >> 1, hv = idx & 1;
        int p = qb0 - 64 + kk;
        uh8 v = (uh8)0;
        if ((unsigned)p < (unsigned)T)
            v = *(const uh8*)&kt_[(kvb * T + p) * 16 + hv * 8];
        *(uh8*)&s_k[kk][hv * 8] = v;
    }
    for (int idx = tid; idx < 432; idx += 256) {   // 16 rows x 27 uh8
        int d = idx / 27, c8 = idx % 27;
        int kk0 = c8 * 8;
        int p0 = qb0 - 64 + kk0;
        uh8 v = (uh8)0;
        if (p0 >= 0 && p0 + 7 < T) {
            v = *(const uh8*)&vt[(kvb * 16 + d) * T + p0];
        } else {
#pragma unroll
            for (int j = 0; j < 8; j++) {
                int p = p0 + j;
                v[j] = ((unsigned)p < (unsigned)T)
                     ? vt[(kvb * 16 + d) * T + p] : (u16t)0;
            }
        }
        *(uh8*)&s_v[d][kk0] = v;
    }
    __syncthreads();

    const int l  = tid & 63;
    const int wv = tid >> 6;
    const int lr = l & 15;
    const int lq = l >> 4;
    const int qt0 = qb0 + wv * 16;

    bfrag Bq = (bfrag)0;   // zero for lq>=2 (d padded 16->32)
    if (lq < 2)
        Bq = *(const bfrag*)&qt[(bf * T + qt0 + lr) * 64 + h * 16 + lq * 8];

    f32x4 sf[9];
#pragma unroll
    for (int kti = 0; kti < 9; kti++) {
        const u16t* ap = (lq < 2) ? &s_k[wv * 16 + kti * 16 + lr][lq * 8]
                                  : &s_zero[0];
        bfrag A = *(const bfrag*)ap;
        sf[kti] = __builtin_amdgcn_mfma_f32_16x16x32_bf16(
            A, Bq, (f32x4){0.f, 0.f, 0.f, 0.f}, 0, 0, 0);
    }

    float m = -3.0e38f;
#pragma unroll
    for (int kti = 0; kti < 9; kti++) {
#pragma unroll
        for (int j = 0; j < 4; j++) {
            int rk = kti * 16 + lq * 4 + j;
            int dq = rk - lr;
            int p  = qt0 - 64 + rk;
            float s = sf[kti][j];
            s = (dq >= 0 && dq <= 128 && p < T) ? s : -1.0e30f;
            sf[kti][j] = s;
            m = fmaxf(m, s);
        }
    }
    m = fmaxf(m, __shfl_xor(m, 16));
    m = fmaxf(m, __shfl_xor(m, 32));

    float lsum = 0.f;
#pragma unroll
    for (int kti = 0; kti < 9; kti++) {
#pragma unroll
        for (int j = 0; j < 4; j++) {
            float e = __expf(sf[kti][j] - m);
            sf[kti][j] = e;
            lsum += e;
        }
    }
    lsum += __shfl_xor(lsum, 16);
    lsum += __shfl_xor(lsum, 32);

#pragma unroll
    for (int kti = 0; kti < 9; kti++) {
        ushort4 pk;
        pk.x = fbf(sf[kti][0]); pk.y = fbf(sf[kti][1]);
        pk.z = fbf(sf[kti][2]); pk.w = fbf(sf[kti][3]);
        *(ushort4*)&s_p[wv][lr][kti * 16 + lq * 4] = pk;
    }
    {
        ushort4 z; z.x = 0; z.y = 0; z.z = 0; z.w = 0;
        *(ushort4*)&s_p[wv][lr][144 + lq * 4] = z;   // zero tail rk 144..159
    }
    __syncthreads();

    f32x4 oa = (f32x4){0.f, 0.f, 0.f, 0.f};
#pragma unroll
    for (int kc = 0; kc < 5; kc++) {
        bfrag Av = *(const bfrag*)&s_v[lr][wv * 16 + kc * 32 + lq * 8];
        bfrag Bp = *(const bfrag*)&s_p[wv][lr][kc * 32 + lq * 8];
        oa = __builtin_amdgcn_mfma_f32_16x16x32_bf16(Av, Bp, oa, 0, 0, 0);
    }
    const float inv = 1.0f / lsum;
    ushort4 ov;
    ov.x = fbf(oa[0] * inv); ov.y = fbf(oa[1] * inv);
    ov.z = fbf(oa[2] * inv); ov.w = fbf(oa[3] * inv);
    *(ushort4*)&ob[(bf * T + qt0 + lr) * 64 + h * 16 + lq * 4] = ov;
}

// ---------------------------------------------------------------------------
// MFMA fused o-projection + BN + LeakyReLU + final conv1x1 (proven round 7;
// y input bf16).
// ---------------------------------------------------------------------------
__global__ __launch_bounds__(256) void final_mfma_k(
    const u16t* __restrict__ ob, const u16t* __restrict__ yb,
    const u16t* __restrict__ wo, const float* __restrict__ obias,
    const float* __restrict__ sg, const float* __restrict__ sb,
    const float* __restrict__ sm, const float* __restrict__ sv,
    const u16t* __restrict__ wsao, const float* __restrict__ swb,
    float* __restrict__ out)
{
    constexpr int F = 64, T = 512, TT = 64, P = 72;
    __shared__ __align__(16) u16t s_ob[64][P];
    __shared__ __align__(16) u16t s_y2[64][P];
    __shared__ __align__(16) u16t s_att[64][P];
    __shared__ float s_sc[128], s_sh[128];

    const int tid = threadIdx.x;
    const int t0 = blockIdx.x * TT;
    const int f = blockIdx.y, b = blockIdx.z;

    if (tid < 128) {
        float sc = sg[tid] * rsqrtf(sv[tid] + 1e-5f);
        s_sc[tid] = sc;
        s_sh[tid] = sb[tid] - sm[tid] * sc;
    }
    __syncthreads();

    for (int i = tid; i < 512; i += 256) {
        int tt = i >> 3, c0 = (i & 7) * 8;
        long gi = (((long)b * F + f) * T + t0 + tt) * 64 + c0;
        *(uh8*)&s_ob[tt][c0] = *(const uh8*)&ob[gi];
        uh8 raw = *(const uh8*)&yb[gi];
        uh8 v;
#pragma unroll
        for (int j = 0; j < 8; j++) {
            float xv = bfu(raw[j]);
            float xn = fmaf(xv, s_sc[c0 + j], s_sh[c0 + j]);
            v[j] = fbf(fmaxf(xn, 0.01f * xn));
        }
        *(uh8*)&s_y2[tt][c0] = v;
    }
    __syncthreads();

    const int l  = tid & 63;
    const int wv = tid >> 6;
    const int lr = l & 15;
    const int lq = l >> 4;
    const int tbase = wv * 16 + lr;
    const int cbase = lq * 8;

    f32x4 acc1[4];
#pragma unroll
    for (int i = 0; i < 4; i++) acc1[i] = (f32x4){0.f, 0.f, 0.f, 0.f};
#pragma unroll
    for (int kb = 0; kb < 2; kb++) {
        bfrag B = *(const bfrag*)&s_ob[tbase][kb * 32 + cbase];
#pragma unroll
        for (int ct = 0; ct < 4; ct++) {
            bfrag A = *(const bfrag*)&wo[(kb * 64 + ct * 16 + lr) * 32 + lq * 8];
            acc1[ct] = __builtin_amdgcn_mfma_f32_16x16x32_bf16(A, B, acc1[ct], 0, 0, 0);
        }
    }
#pragma unroll
    for (int ct = 0; ct < 4; ct++) {
        int co = ct * 16 + lq * 4;
        float4 bi = *(const float4*)&obias[co];
#pragma unroll
        for (int j = 0; j < 4; j++) {
            float a = acc1[ct][j] + ((j == 0) ? bi.x : (j == 1) ? bi.y : (j == 2) ? bi.z : bi.w);
            int cg = 64 + co + j;
            float xn = fmaf(a, s_sc[cg], s_sh[cg]);
            s_att[tbase][co + j] = fbf(fmaxf(xn, 0.01f * xn));
        }
    }
    __syncthreads();

    f32x4 acc2[4];
#pragma unroll
    for (int i = 0; i < 4; i++) acc2[i] = (f32x4){0.f, 0.f, 0.f, 0.f};
#pragma unroll
    for (int kb = 0; kb < 4; kb++) {
        bfrag B = (kb < 2) ? *(const bfrag*)&s_y2[tbase][kb * 32 + cbase]
                           : *(const bfrag*)&s_att[tbase][(kb - 2) * 32 + cbase];
#pragma unroll
        for (int ct = 0; ct < 4; ct++) {
            bfrag A = *(const bfrag*)&wsao[(kb * 64 + ct * 16 + lr) * 32 + lq * 8];
            acc2[ct] = __builtin_amdgcn_mfma_f32_16x16x32_bf16(A, B, acc2[ct], 0, 0, 0);
        }
    }
    const int t = t0 + wv * 16 + lr;
#pragma unroll
    for (int ct = 0; ct < 4; ct++) {
        int co0 = ct * 16 + lq * 4;
        float4 bs = *(const float4*)&swb[co0];
#pragma unroll
        for (int j = 0; j < 4; j++) {
            float bv = (j == 0) ? bs.x : (j == 1) ? bs.y : (j == 2) ? bs.z : bs.w;
            out[(((long)b * 64 + co0 + j) * F + f) * T + t] = acc2[ct][j] + bv;
        }
    }
}

// ---------------------------------------------------------------------------
extern "C" void kernel_launch(void* const* d_in, const int* in_sizes, int n_in,
                              void* d_out, int out_size, void* d_ws, size_t ws_size,
                              hipStream_t stream)
{
    (void)in_sizes; (void)n_in; (void)out_size; (void)ws_size;

    const float* x      = (const float*)d_in[0];
    const float* bd0_g  = (const float*)d_in[1];
    const float* bd0_b  = (const float*)d_in[2];
    const float* bd0_m  = (const float*)d_in[3];
    const float* bd0_v  = (const float*)d_in[4];
    const float* bd0_w  = (const float*)d_in[5];
    const float* bd0_wb = (const float*)d_in[6];
    const float* bd1_g  = (const float*)d_in[7];
    const float* bd1_b  = (const float*)d_in[8];
    const float* bd1_m  = (const float*)d_in[9];
    const float* bd1_v  = (const float*)d_in[10];
    const float* bd1_w  = (const float*)d_in[11];
    const float* bd1_wb = (const float*)d_in[12];
    const float* bdo_g  = (const float*)d_in[13];
    const float* bdo_b  = (const float*)d_in[14];
    const float* bdo_m  = (const float*)d_in[15];
    const float* bdo_v  = (const float*)d_in[16];
    const float* bdo_w  = (const float*)d_in[17];
    const float* bdo_wb = (const float*)d_in[18];
    const float* qkv_w  = (const float*)d_in[19];
    const float* qkv_b  = (const float*)d_in[20];
    const float* o_w    = (const float*)d_in[21];
    const float* o_b    = (const float*)d_in[22];
    const float* sao_g  = (const float*)d_in[23];
    const float* sao_b  = (const float*)d_in[24];
    const float* sao_m  = (const float*)d_in[25];
    const float* sao_v  = (const float*)d_in[26];
    const float* sao_w  = (const float*)d_in[27];
    const float* sao_wb = (const float*)d_in[28];

    char* ws = (char*)d_ws;
    // ws map (bytes), peak 67.4MB (ws >= 80MB proven by rounds 2/3):
    //   [0.0 , 16.8M)  xt bf16 [b][f][t][64]  -> q_t (after conv2) -> obf
    //                  (obf aliases q_t in-place: see attn_mfma_k note)
    //   [16.8, 33.6M)  a0|a1 bf16             -> k_t bf16 [b][f][h][t][16]
    //   [33.6, 50.3M)  v_t bf16 [b][f][h][d][t]
    //   [50.3, 67.1M)  ybf bf16 [b][f][t][64]
    //   [67.1, 67.4M)  wpack bf16 (144384 entries)
    u16t* xt  = (u16t*)(ws);
    u16t* a0  = (u16t*)(ws + 16777216);
    u16t* a1  = (u16t*)(ws + 25165824);
    u16t* q_t = (u16t*)(ws);
    u16t* k_t = (u16t*)(ws + 16777216);
    u16t* v_t = (u16t*)(ws + 33554432);
    u16t* ybf = (u16t*)(ws + 50331648);
    u16t* obf = q_t;                       // in-place alias (safe, see note)
    u16t* wpk = (u16t*)(ws + 67108864);

    dim3 blk(256);
    dim3 gconv(8, 64, 4);   // T/64, F, B

    hipLaunchKernelGGL(prep_x_k, gconv, blk, 0, stream, x, xt);
    hipLaunchKernelGGL(prep_w_k, dim3(564), blk, 0, stream,
        bd0_w, bd1_w, bdo_w, o_w, sao_w, qkv_w, wpk);
    hipLaunchKernelGGL((conv3x3_mfma_k<64, 32, true>), gconv, blk, 0, stream,
        xt, nullptr, nullptr, bd0_g, bd0_b, bd0_m, bd0_v, wpk, bd0_wb, (void*)a0);
    hipLaunchKernelGGL((conv3x3_mfma_k<96, 32, true>), gconv, blk, 0, stream,
        xt, a0, nullptr, bd1_g, bd1_b, bd1_m, bd1_v, wpk + 18432, bd1_wb, (void*)a1);
    hipLaunchKernelGGL((conv3x3_mfma_k<128, 64, true>), gconv, blk, 0, stream,
        xt, a0, a1, bdo_g, bdo_b, bdo_m, bdo_v, wpk + 46080, bdo_wb, (void*)ybf);
    hipLaunchKernelGGL(qkv_mfma_k, gconv, blk, 0, stream,
        ybf, wpk + 132096, qkv_b, q_t, k_t, v_t);
    hipLaunchKernelGGL(attn_mfma_k, dim3(32, 64, 4), blk, 0, stream,
        q_t, k_t, v_t, obf);
    hipLaunchKernelGGL(final_mfma_k, gconv, blk, 0, stream,
        obf, ybf, wpk + 119808, o_b, sao_g, sao_b, sao_m, sao_v,
        wpk + 123904, sao_wb, (float*)d_out);
}

// Round 10
// 211.213 us; speedup vs baseline: 6.0776x; 1.2234x over previous
//
#include <hip/hip_runtime.h>
#include <hip/hip_bf16.h>

typedef unsigned short u16t;
typedef __attribute__((ext_vector_type(8))) short bfrag;      // 8 bf16 bits
typedef __attribute__((ext_vector_type(4))) float f32x4;      // MFMA acc
typedef __attribute__((ext_vector_type(8))) unsigned short uh8;

__device__ __forceinline__ float bfu(u16t u) {
    union { unsigned int i; float f; } c;
    c.i = ((unsigned int)u) << 16;
    return c.f;
}
__device__ __forceinline__ u16t fbf(float f) {
    __hip_bfloat16 h = __float2bfloat16(f);
    return *reinterpret_cast<u16t*>(&h);
}

// ---------------------------------------------------------------------------
// x [b][64c][64f][512t] fp32  ->  x_t [b][f][t][64c] bf16
// ---------------------------------------------------------------------------
__global__ __launch_bounds__(256) void prep_x_k(
    const float* __restrict__ x, u16t* __restrict__ xt)
{
    constexpr int F = 64, T = 512;
    __shared__ u16t su[64][74];
    const int tid = threadIdx.x;
    const int t0 = blockIdx.x * 64;
    const int f = blockIdx.y, b = blockIdx.z;

#pragma unroll
    for (int p = 0; p < 16; p++) {
        int i = tid + 256 * p;
        int c = i >> 6, t = i & 63;
        su[c][t] = fbf(x[(((long)b * 64 + c) * F + f) * T + t0 + t]);
    }
    __syncthreads();
#pragma unroll
    for (int p = 0; p < 2; p++) {
        int i = tid + 256 * p;
        int t = i >> 3, c8 = i & 7;
        uh8 v;
#pragma unroll
        for (int j = 0; j < 8; j++) v[j] = su[c8 * 8 + j][t];
        *(uh8*)&xt[(((long)b * F + f) * T + t0 + t) * 64 + c8 * 8] = v;
    }
}

// ---------------------------------------------------------------------------
// Pack weights fp32 -> bf16 fragments.
// Convs (lane-ordered, cb outermost): seg idx = (((cb*9+kk)*NCOT+ct)*64+l)*8+j
//   with co = ct*16 + (l&15), kin = cb*32 + (l>>4)*8 + j, kh=kk/3, kw=kk%3.
// conv0 @0 (18432) | conv1 @18432 (27648) | conv2 @46080 (73728)
// o_w @119808 (4096) | sao_w @123904 (8192) | qkv_w @132096 (12288)
// (o/sao/qkv keep the round-7-proven [kb][co][32] A-frag layout)
// ---------------------------------------------------------------------------
__global__ __launch_bounds__(256) void prep_w_k(
    const float* __restrict__ w0, const float* __restrict__ w1,
    const float* __restrict__ w2, const float* __restrict__ ow,
    const float* __restrict__ sw, const float* __restrict__ qw,
    u16t* __restrict__ wp)
{
    int idx = blockIdx.x * 256 + threadIdx.x;
    if (idx >= 144384) return;
    if (idx < 119808) {
        int C_IN, C_OUT, e;
        const float* src;
        if (idx < 18432)      { C_IN = 64;  C_OUT = 32; src = w0; e = idx; }
        else if (idx < 46080) { C_IN = 96;  C_OUT = 32; src = w1; e = idx - 18432; }
        else                  { C_IN = 128; C_OUT = 64; src = w2; e = idx - 46080; }
        int NCOT = C_OUT / 16;
        int j  = e & 7;
        int l  = (e >> 3) & 63;
        int r  = e >> 9;
        int ct = r % NCOT;
        int r2 = r / NCOT;
        int kk = r2 % 9;
        int cb = r2 / 9;
        int co  = ct * 16 + (l & 15);
        int kin = cb * 32 + (l >> 4) * 8 + j;
        int kh = kk / 3, kw = kk % 3;
        wp[idx] = fbf(src[((co * C_IN + kin) * 3 + kh) * 3 + kw]);
    } else if (idx < 123904) {
        int e = idx - 119808;
        int ks = e & 31, co = (e >> 5) & 63, kb = e >> 11;
        wp[idx] = fbf(ow[co * 64 + kb * 32 + ks]);
    } else if (idx < 132096) {
        int e = idx - 123904;
        int ks = e & 31, co = (e >> 5) & 63, kb = e >> 11;
        wp[idx] = fbf(sw[co * 128 + kb * 32 + ks]);
    } else {
        int e = idx - 132096;
        int ks = e & 31, co = (e >> 5) % 192, kb = e / 6144;
        wp[idx] = fbf(qw[co * 64 + kb * 32 + ks]);
    }
}

// ---------------------------------------------------------------------------
// MFMA fused BN + LeakyReLU + 3x3 conv, chunked K with BOTH operands in LDS.
// Per 32-input-channel chunk: stage halo tile s_x[3][66][40] + that chunk's
// weights s_w (lane-ordered contiguous -> conflict-free ds_read_b128).
// Zero global loads in the MFMA loop.  LDS 53.7KB (C_OUT=64, 3 blocks/CU)
// or 34.8KB (C_OUT=32, 4 blocks/CU).
// ---------------------------------------------------------------------------
template<int C_IN, int C_OUT, bool OBF>
__global__ __launch_bounds__(256) void conv3x3_mfma_k(
    const u16t* __restrict__ s0, const u16t* __restrict__ s1,
    const u16t* __restrict__ s2,
    const float* __restrict__ gg, const float* __restrict__ bb,
    const float* __restrict__ mm, const float* __restrict__ vv,
    const u16t* __restrict__ wseg, const float* __restrict__ wb,
    void* __restrict__ dstv)
{
    constexpr int F = 64, T = 512, TT = 64;
    constexpr int NCH  = C_IN / 32;       // K chunks
    constexpr int NCOT = C_OUT / 16;      // co tiles
    constexpr int WT   = 9 * NCOT * 64;   // uh8 chunks of weights per cb

    __shared__ __align__(16) u16t s_x[3][66][40];
    __shared__ __align__(16) u16t s_w[WT * 8];
    __shared__ float s_scA[C_IN], s_shA[C_IN];

    const int tid = threadIdx.x;
    const int t0 = blockIdx.x * TT;
    const int f  = blockIdx.y;
    const int b  = blockIdx.z;

    if (tid < C_IN) {
        float s = gg[tid] * rsqrtf(vv[tid] + 1e-5f);
        s_scA[tid] = s;
        s_shA[tid] = bb[tid] - mm[tid] * s;
    }

    const int l  = tid & 63;
    const int wv = tid >> 6;
    const int lr = l & 15;
    const int lq = l >> 4;
    const int tbase = wv * 16 + lr;

    f32x4 acc[NCOT];
#pragma unroll
    for (int i = 0; i < NCOT; i++) acc[i] = (f32x4){0.f, 0.f, 0.f, 0.f};

    for (int ch = 0; ch < NCH; ch++) {
        __syncthreads();   // tables ready (ch=0) / prev chunk consumed

        for (int idx = tid; idx < 792 + WT; idx += 256) {
            if (idx < 792) {
                int row = idx >> 2, oct = idx & 3;   // oct fixed per thread
                int kh = (row >= 132) ? 2 : ((row >= 66) ? 1 : 0);
                int tp = row - kh * 66;
                int fi = f + kh - 1;
                int tg = t0 + tp - 1;
                int gc8 = ch * 4 + oct;
                uh8 v = (uh8)0;
                if ((unsigned)fi < (unsigned)F && (unsigned)tg < (unsigned)T) {
                    const u16t* sp; int coff, cw;
                    if (gc8 < 8)       { sp = s0; coff = gc8 * 8;        cw = 64; }
                    else if (gc8 < 12) { sp = s1; coff = (gc8 - 8) * 8;  cw = 32; }
                    else               { sp = s2; coff = (gc8 - 12) * 8; cw = 32; }
                    uh8 raw = *(const uh8*)&sp[(((long)b * F + fi) * T + tg) * cw + coff];
#pragma unroll
                    for (int j = 0; j < 8; j++) {
                        float xv = bfu(raw[j]);
                        float xn = fmaf(xv, s_scA[gc8 * 8 + j], s_shA[gc8 * 8 + j]);
                        v[j] = fbf(fmaxf(xn, 0.01f * xn));
                    }
                }
                *(uh8*)&s_x[kh][tp][oct * 8] = v;
            } else {
                int w = idx - 792;
                *(uh8*)&s_w[w * 8] = *(const uh8*)&wseg[((long)ch * WT + w) * 8];
            }
        }
        __syncthreads();

#pragma unroll
        for (int kk = 0; kk < 9; kk++) {
            const int kh = kk / 3, kw = kk % 3;
            bfrag B = *(const bfrag*)&s_x[kh][tbase + kw][lq * 8];
#pragma unroll
            for (int ct = 0; ct < NCOT; ct++) {
                bfrag A = *(const bfrag*)&s_w[((kk * NCOT + ct) * 64 + l) * 8];
                acc[ct] = __builtin_amdgcn_mfma_f32_16x16x32_bf16(A, B, acc[ct], 0, 0, 0);
            }
        }
    }

    const int t = t0 + wv * 16 + lr;
#pragma unroll
    for (int ct = 0; ct < NCOT; ct++) {
        int co0 = ct * 16 + lq * 4;
        float4 bs = *(const float4*)&wb[co0];
        long obase = (((long)b * F + f) * T + t) * C_OUT + co0;
        if (OBF) {
            u16t* dp = (u16t*)dstv;
            ushort4 pk;
            pk.x = fbf(acc[ct][0] + bs.x);
            pk.y = fbf(acc[ct][1] + bs.y);
            pk.z = fbf(acc[ct][2] + bs.z);
            pk.w = fbf(acc[ct][3] + bs.w);
            *(ushort4*)&dp[obase] = pk;
        } else {
            float* dp = (float*)dstv;
            float4 ov;
            ov.x = acc[ct][0] + bs.x;
            ov.y = acc[ct][1] + bs.y;
            ov.z = acc[ct][2] + bs.z;
            ov.w = acc[ct][3] + bs.w;
            *(float4*)&dp[obase] = ov;
        }
    }
}

// ---------------------------------------------------------------------------
// MFMA qkv projection (proven round 9).  ybf bf16 [b][f][t][64] ->
// Q [b][f][t][64] (x0.25), K [b][f][h][t][16], V^T [b][f][h][d][t].
// ---------------------------------------------------------------------------
__global__ __launch_bounds__(256) void qkv_mfma_k(
    const u16t* __restrict__ ybf, const u16t* __restrict__ wq,
    const float* __restrict__ qbias,
    u16t* __restrict__ q_t, u16t* __restrict__ k_t, u16t* __restrict__ v_t)
{
    constexpr int F = 64, T = 512;
    __shared__ __align__(16) u16t s_y[64][72];
    const int tid = threadIdx.x;
    const int t0 = blockIdx.x * 64;
    const int f = blockIdx.y, b = blockIdx.z;
    const long bf = (long)b * F + f;

    for (int i = tid; i < 512; i += 256) {
        int tt = i >> 3, c0 = (i & 7) * 8;
        *(uh8*)&s_y[tt][c0] = *(const uh8*)&ybf[(bf * T + t0 + tt) * 64 + c0];
    }
    __syncthreads();

    const int l = tid & 63, wv = tid >> 6;
    const int lr = l & 15, lq = l >> 4;
    const int tb = wv * 16 + lr;

    bfrag B0 = *(const bfrag*)&s_y[tb][lq * 8];
    bfrag B1 = *(const bfrag*)&s_y[tb][32 + lq * 8];

    f32x4 acc[12];
#pragma unroll
    for (int i = 0; i < 12; i++) acc[i] = (f32x4){0.f, 0.f, 0.f, 0.f};
#pragma unroll
    for (int ct = 0; ct < 12; ct++) {
        bfrag A0 = *(const bfrag*)&wq[(ct * 16 + lr) * 32 + lq * 8];
        acc[ct] = __builtin_amdgcn_mfma_f32_16x16x32_bf16(A0, B0, acc[ct], 0, 0, 0);
    }
#pragma unroll
    for (int ct = 0; ct < 12; ct++) {
        bfrag A1 = *(const bfrag*)&wq[(192 + ct * 16 + lr) * 32 + lq * 8];
        acc[ct] = __builtin_amdgcn_mfma_f32_16x16x32_bf16(A1, B1, acc[ct], 0, 0, 0);
    }

    const int t = t0 + tb;
#pragma unroll
    for (int ct = 0; ct < 12; ct++) {
        int co0 = ct * 16 + lq * 4;
        float4 bi = *(const float4*)&qbias[co0];
        float a0 = acc[ct][0] + bi.x, a1 = acc[ct][1] + bi.y;
        float a2 = acc[ct][2] + bi.z, a3 = acc[ct][3] + bi.w;
        if (co0 < 64) {
            ushort4 pk;
            pk.x = fbf(a0 * 0.25f); pk.y = fbf(a1 * 0.25f);
            pk.z = fbf(a2 * 0.25f); pk.w = fbf(a3 * 0.25f);
            *(ushort4*)&q_t[(bf * T + t) * 64 + co0] = pk;
        } else if (co0 < 128) {
            int hh = (co0 - 64) >> 4, d0 = (co0 - 64) & 15;
            ushort4 pk;
            pk.x = fbf(a0); pk.y = fbf(a1); pk.z = fbf(a2); pk.w = fbf(a3);
            *(ushort4*)&k_t[((bf * 4 + hh) * T + t) * 16 + d0] = pk;
        } else {
            int hh = (co0 - 128) >> 4, d0 = (co0 - 128) & 15;
            long vb = (bf * 4 + hh) * 16;
            v_t[(vb + d0 + 0) * T + t] = fbf(a0);
            v_t[(vb + d0 + 1) * T + t] = fbf(a1);
            v_t[(vb + d0 + 2) * T + t] = fbf(a2);
            v_t[(vb + d0 + 3) * T + t] = fbf(a3);
        }
    }
}

// ---------------------------------------------------------------------------
// MFMA banded attention (proven round 9).  ob aliases q_t in-place (each
// block writes exactly the tile it read Q from).
// ---------------------------------------------------------------------------
__global__ __launch_bounds__(256) void attn_mfma_k(
    const u16t* __restrict__ qt, const u16t* __restrict__ kt_,
    const u16t* __restrict__ vt, u16t* __restrict__ ob)
{
    constexpr int T = 512, F = 64;
    const int qc = blockIdx.x & 7;
    const int h  = blockIdx.x >> 3;
    const int f = blockIdx.y, b = blockIdx.z;
    const int qb0 = qc * 64;
    const int tid = threadIdx.x;
    const long bf = (long)b * F + f;
    const long kvb = bf * 4 + h;

    __shared__ __align__(16) u16t s_k[192][24];
    __shared__ __align__(16) u16t s_v[16][216];
    __shared__ __align__(16) u16t s_p[4][16][168];
    __shared__ __align__(16) u16t s_zero[8];

    if (tid < 8) s_zero[tid] = 0;

    for (int idx = tid; idx < 384; idx += 256) {
        int kk = idx >> 1, hv = idx & 1;
        int p = qb0 - 64 + kk;
        uh8 v = (uh8)0;
        if ((unsigned)p < (unsigned)T)
            v = *(const uh8*)&kt_[(kvb * T + p) * 16 + hv * 8];
        *(uh8*)&s_k[kk][hv * 8] = v;
    }
    for (int idx = tid; idx < 432; idx += 256) {
        int d = idx / 27, c8 = idx % 27;
        int kk0 = c8 * 8;
        int p0 = qb0 - 64 + kk0;
        uh8 v = (uh8)0;
        if (p0 >= 0 && p0 + 7 < T) {
            v = *(const uh8*)&vt[(kvb * 16 + d) * T + p0];
        } else {
#pragma unroll
            for (int j = 0; j < 8; j++) {
                int p = p0 + j;
                v[j] = ((unsigned)p < (unsigned)T)
                     ? vt[(kvb * 16 + d) * T + p] : (u16t)0;
            }
        }
        *(uh8*)&s_v[d][kk0] = v;
    }
    __syncthreads();

    const int l  = tid & 63;
    const int wv = tid >> 6;
    const int lr = l & 15;
    const int lq = l >> 4;
    const int qt0 = qb0 + wv * 16;

    bfrag Bq = (bfrag)0;
    if (lq < 2)
        Bq = *(const bfrag*)&qt[(bf * T + qt0 + lr) * 64 + h * 16 + lq * 8];

    f32x4 sf[9];
#pragma unroll
    for (int kti = 0; kti < 9; kti++) {
        const u16t* ap = (lq < 2) ? &s_k[wv * 16 + kti * 16 + lr][lq * 8]
                                  : &s_zero[0];
        bfrag A = *(const bfrag*)ap;
        sf[kti] = __builtin_amdgcn_mfma_f32_16x16x32_bf16(
            A, Bq, (f32x4){0.f, 0.f, 0.f, 0.f}, 0, 0, 0);
    }

    float m = -3.0e38f;
#pragma unroll
    for (int kti = 0; kti < 9; kti++) {
#pragma unroll
        for (int j = 0; j < 4; j++) {
            int rk = kti * 16 + lq * 4 + j;
            int dq = rk - lr;
            int p  = qt0 - 64 + rk;
            float s = sf[kti][j];
            s = (dq >= 0 && dq <= 128 && p < T) ? s : -1.0e30f;
            sf[kti][j] = s;
            m = fmaxf(m, s);
        }
    }
    m = fmaxf(m, __shfl_xor(m, 16));
    m = fmaxf(m, __shfl_xor(m, 32));

    float lsum = 0.f;
#pragma unroll
    for (int kti = 0; kti < 9; kti++) {
#pragma unroll
        for (int j = 0; j < 4; j++) {
            float e = __expf(sf[kti][j] - m);
            sf[kti][j] = e;
            lsum += e;
        }
    }
    lsum += __shfl_xor(lsum, 16);
    lsum += __shfl_xor(lsum, 32);

#pragma unroll
    for (int kti = 0; kti < 9; kti++) {
        ushort4 pk;
        pk.x = fbf(sf[kti][0]); pk.y = fbf(sf[kti][1]);
        pk.z = fbf(sf[kti][2]); pk.w = fbf(sf[kti][3]);
        *(ushort4*)&s_p[wv][lr][kti * 16 + lq * 4] = pk;
    }
    {
        ushort4 z; z.x = 0; z.y = 0; z.z = 0; z.w = 0;
        *(ushort4*)&s_p[wv][lr][144 + lq * 4] = z;
    }
    __syncthreads();

    f32x4 oa = (f32x4){0.f, 0.f, 0.f, 0.f};
#pragma unroll
    for (int kc = 0; kc < 5; kc++) {
        bfrag Av = *(const bfrag*)&s_v[lr][wv * 16 + kc * 32 + lq * 8];
        bfrag Bp = *(const bfrag*)&s_p[wv][lr][kc * 32 + lq * 8];
        oa = __builtin_amdgcn_mfma_f32_16x16x32_bf16(Av, Bp, oa, 0, 0, 0);
    }
    const float inv = 1.0f / lsum;
    ushort4 ov;
    ov.x = fbf(oa[0] * inv); ov.y = fbf(oa[1] * inv);
    ov.z = fbf(oa[2] * inv); ov.w = fbf(oa[3] * inv);
    *(ushort4*)&ob[(bf * T + qt0 + lr) * 64 + h * 16 + lq * 4] = ov;
}

// ---------------------------------------------------------------------------
// MFMA fused o-projection + BN + LeakyReLU + final conv1x1 (proven round 9).
// ---------------------------------------------------------------------------
__global__ __launch_bounds__(256) void final_mfma_k(
    const u16t* __restrict__ ob, const u16t* __restrict__ yb,
    const u16t* __restrict__ wo, const float* __restrict__ obias,
    const float* __restrict__ sg, const float* __restrict__ sb,
    const float* __restrict__ sm, const float* __restrict__ sv,
    const u16t* __restrict__ wsao, const float* __restrict__ swb,
    float* __restrict__ out)
{
    constexpr int F = 64, T = 512, TT = 64, P = 72;
    __shared__ __align__(16) u16t s_ob[64][P];
    __shared__ __align__(16) u16t s_y2[64][P];
    __shared__ __align__(16) u16t s_att[64][P];
    __shared__ float s_sc[128], s_sh[128];

    const int tid = threadIdx.x;
    const int t0 = blockIdx.x * TT;
    const int f = blockIdx.y, b = blockIdx.z;

    if (tid < 128) {
        float sc = sg[tid] * rsqrtf(sv[tid] + 1e-5f);
        s_sc[tid] = sc;
        s_sh[tid] = sb[tid] - sm[tid] * sc;
    }
    __syncthreads();

    for (int i = tid; i < 512; i += 256) {
        int tt = i >> 3, c0 = (i & 7) * 8;
        long gi = (((long)b * F + f) * T + t0 + tt) * 64 + c0;
        *(uh8*)&s_ob[tt][c0] = *(const uh8*)&ob[gi];
        uh8 raw = *(const uh8*)&yb[gi];
        uh8 v;
#pragma unroll
        for (int j = 0; j < 8; j++) {
            float xv = bfu(raw[j]);
            float xn = fmaf(xv, s_sc[c0 + j], s_sh[c0 + j]);
            v[j] = fbf(fmaxf(xn, 0.01f * xn));
        }
        *(uh8*)&s_y2[tt][c0] = v;
    }
    __syncthreads();

    const int l  = tid & 63;
    const int wv = tid >> 6;
    const int lr = l & 15;
    const int lq = l >> 4;
    const int tbase = wv * 16 + lr;
    const int cbase = lq * 8;

    f32x4 acc1[4];
#pragma unroll
    for (int i = 0; i < 4; i++) acc1[i] = (f32x4){0.f, 0.f, 0.f, 0.f};
#pragma unroll
    for (int kb = 0; kb < 2; kb++) {
        bfrag B = *(const bfrag*)&s_ob[tbase][kb * 32 + cbase];
#pragma unroll
        for (int ct = 0; ct < 4; ct++) {
            bfrag A = *(const bfrag*)&wo[(kb * 64 + ct * 16 + lr) * 32 + lq * 8];
            acc1[ct] = __builtin_amdgcn_mfma_f32_16x16x32_bf16(A, B, acc1[ct], 0, 0, 0);
        }
    }
#pragma unroll
    for (int ct = 0; ct < 4; ct++) {
        int co = ct * 16 + lq * 4;
        float4 bi = *(const float4*)&obias[co];
#pragma unroll
        for (int j = 0; j < 4; j++) {
            float a = acc1[ct][j] + ((j == 0) ? bi.x : (j == 1) ? bi.y : (j == 2) ? bi.z : bi.w);
            int cg = 64 + co + j;
            float xn = fmaf(a, s_sc[cg], s_sh[cg]);
            s_att[tbase][co + j] = fbf(fmaxf(xn, 0.01f * xn));
        }
    }
    __syncthreads();

    f32x4 acc2[4];
#pragma unroll
    for (int i = 0; i < 4; i++) acc2[i] = (f32x4){0.f, 0.f, 0.f, 0.f};
#pragma unroll
    for (int kb = 0; kb < 4; kb++) {
        bfrag B = (kb < 2) ? *(const bfrag*)&s_y2[tbase][kb * 32 + cbase]
                           : *(const bfrag*)&s_att[tbase][(kb - 2) * 32 + cbase];
#pragma unroll
        for (int ct = 0; ct < 4; ct++) {
            bfrag A = *(const bfrag*)&wsao[(kb * 64 + ct * 16 + lr) * 32 + lq * 8];
            acc2[ct] = __builtin_amdgcn_mfma_f32_16x16x32_bf16(A, B, acc2[ct], 0, 0, 0);
        }
    }
    const int t = t0 + wv * 16 + lr;
#pragma unroll
    for (int ct = 0; ct < 4; ct++) {
        int co0 = ct * 16 + lq * 4;
        float4 bs = *(const float4*)&swb[co0];
#pragma unroll
        for (int j = 0; j < 4; j++) {
            float bv = (j == 0) ? bs.x : (j == 1) ? bs.y : (j == 2) ? bs.z : bs.w;
            out[(((long)b * 64 + co0 + j) * F + f) * T + t] = acc2[ct][j] + bv;
        }
    }
}

// ---------------------------------------------------------------------------
extern "C" void kernel_launch(void* const* d_in, const int* in_sizes, int n_in,
                              void* d_out, int out_size, void* d_ws, size_t ws_size,
                              hipStream_t stream)
{
    (void)in_sizes; (void)n_in; (void)out_size; (void)ws_size;

    const float* x      = (const float*)d_in[0];
    const float* bd0_g  = (const float*)d_in[1];
    const float* bd0_b  = (const float*)d_in[2];
    const float* bd0_m  = (const float*)d_in[3];
    const float* bd0_v  = (const float*)d_in[4];
    const float* bd0_w  = (const float*)d_in[5];
    const float* bd0_wb = (const float*)d_in[6];
    const float* bd1_g  = (const float*)d_in[7];
    const float* bd1_b  = (const float*)d_in[8];
    const float* bd1_m  = (const float*)d_in[9];
    const float* bd1_v  = (const float*)d_in[10];
    const float* bd1_w  = (const float*)d_in[11];
    const float* bd1_wb = (const float*)d_in[12];
    const float* bdo_g  = (const float*)d_in[13];
    const float* bdo_b  = (const float*)d_in[14];
    const float* bdo_m  = (const float*)d_in[15];
    const float* bdo_v  = (const float*)d_in[16];
    const float* bdo_w  = (const float*)d_in[17];
    const float* bdo_wb = (const float*)d_in[18];
    const float* qkv_w  = (const float*)d_in[19];
    const float* qkv_b  = (const float*)d_in[20];
    const float* o_w    = (const float*)d_in[21];
    const float* o_b    = (const float*)d_in[22];
    const float* sao_g  = (const float*)d_in[23];
    const float* sao_b  = (const float*)d_in[24];
    const float* sao_m  = (const float*)d_in[25];
    const float* sao_v  = (const float*)d_in[26];
    const float* sao_w  = (const float*)d_in[27];
    const float* sao_wb = (const float*)d_in[28];

    char* ws = (char*)d_ws;
    // ws map (bytes), peak 67.4MB (ws >= 80MB proven by rounds 2/3):
    //   [0.0 , 16.8M)  xt bf16 [b][f][t][64]  -> q_t (after conv2) -> obf
    //   [16.8, 33.6M)  a0|a1 bf16             -> k_t bf16 [b][f][h][t][16]
    //   [33.6, 50.3M)  v_t bf16 [b][f][h][d][t]
    //   [50.3, 67.1M)  ybf bf16 [b][f][t][64]
    //   [67.1, 67.4M)  wpack bf16 (144384 entries)
    u16t* xt  = (u16t*)(ws);
    u16t* a0  = (u16t*)(ws + 16777216);
    u16t* a1  = (u16t*)(ws + 25165824);
    u16t* q_t = (u16t*)(ws);
    u16t* k_t = (u16t*)(ws + 16777216);
    u16t* v_t = (u16t*)(ws + 33554432);
    u16t* ybf = (u16t*)(ws + 50331648);
    u16t* obf = q_t;                       // in-place alias (safe)
    u16t* wpk = (u16t*)(ws + 67108864);

    dim3 blk(256);
    dim3 gconv(8, 64, 4);   // T/64, F, B

    hipLaunchKernelGGL(prep_x_k, gconv, blk, 0, stream, x, xt);
    hipLaunchKernelGGL(prep_w_k, dim3(564), blk, 0, stream,
        bd0_w, bd1_w, bdo_w, o_w, sao_w, qkv_w, wpk);
    hipLaunchKernelGGL((conv3x3_mfma_k<64, 32, true>), gconv, blk, 0, stream,
        xt, nullptr, nullptr, bd0_g, bd0_b, bd0_m, bd0_v, wpk, bd0_wb, (void*)a0);
    hipLaunchKernelGGL((conv3x3_mfma_k<96, 32, true>), gconv, blk, 0, stream,
        xt, a0, nullptr, bd1_g, bd1_b, bd1_m, bd1_v, wpk + 18432, bd1_wb, (void*)a1);
    hipLaunchKernelGGL((conv3x3_mfma_k<128, 64, true>), gconv, blk, 0, stream,
        xt, a0, a1, bdo_g, bdo_b, bdo_m, bdo_v, wpk + 46080, bdo_wb, (void*)ybf);
    hipLaunchKernelGGL(qkv_mfma_k, gconv, blk, 0, stream,
        ybf, wpk + 132096, qkv_b, q_t, k_t, v_t);
    hipLaunchKernelGGL(attn_mfma_k, dim3(32, 64, 4), blk, 0, stream,
        q_t, k_t, v_t, obf);
    hipLaunchKernelGGL(final_mfma_k, gconv, blk, 0, stream,
        obf, ybf, wpk + 119808, o_b, sao_g, sao_b, sao_m, sao_v,
        wpk + 123904, sao_wb, (float*)d_out);
}

// Round 11
// 182.393 us; speedup vs baseline: 7.0379x; 1.1580x over previous
//
#include <hip/hip_runtime.h>
#include <hip/hip_bf16.h>

typedef unsigned short u16t;
typedef __attribute__((ext_vector_type(8))) short bfrag;      // 8 bf16 bits
typedef __attribute__((ext_vector_type(4))) float f32x4;      // MFMA acc
typedef __attribute__((ext_vector_type(8))) unsigned short uh8;

__device__ __forceinline__ float bfu(u16t u) {
    union { unsigned int i; float f; } c;
    c.i = ((unsigned int)u) << 16;
    return c.f;
}
__device__ __forceinline__ u16t fbf(float f) {
    __hip_bfloat16 h = __float2bfloat16(f);
    return *reinterpret_cast<u16t*>(&h);
}

// ---------------------------------------------------------------------------
// x [b][64c][64f][512t] fp32 -> three normalized bf16 copies in [b][f][t][64]:
// xn0 = lrelu(bn_bd0(x)), xn1 = lrelu(bn_bd1(x)), xn2 = lrelu(bn_bdo(x))
// ---------------------------------------------------------------------------
__global__ __launch_bounds__(256) void prep_x3_k(
    const float* __restrict__ x,
    const float* __restrict__ g0, const float* __restrict__ b0,
    const float* __restrict__ m0, const float* __restrict__ v0,
    const float* __restrict__ g1, const float* __restrict__ b1,
    const float* __restrict__ m1, const float* __restrict__ v1,
    const float* __restrict__ g2, const float* __restrict__ b2,
    const float* __restrict__ m2, const float* __restrict__ v2,
    u16t* __restrict__ xn0, u16t* __restrict__ xn1, u16t* __restrict__ xn2)
{
    constexpr int F = 64, T = 512;
    __shared__ u16t su[64][74];
    __shared__ float ssc[3][64], ssh[3][64];
    const int tid = threadIdx.x;
    const int t0 = blockIdx.x * 64;
    const int f = blockIdx.y, b = blockIdx.z;

    if (tid < 64) {
        int c = tid;
        float s;
        s = g0[c] * rsqrtf(v0[c] + 1e-5f); ssc[0][c] = s; ssh[0][c] = b0[c] - m0[c] * s;
        s = g1[c] * rsqrtf(v1[c] + 1e-5f); ssc[1][c] = s; ssh[1][c] = b1[c] - m1[c] * s;
        s = g2[c] * rsqrtf(v2[c] + 1e-5f); ssc[2][c] = s; ssh[2][c] = b2[c] - m2[c] * s;
    }
#pragma unroll
    for (int p = 0; p < 16; p++) {
        int i = tid + 256 * p;
        int c = i >> 6, t = i & 63;
        su[c][t] = fbf(x[(((long)b * 64 + c) * F + f) * T + t0 + t]);
    }
    __syncthreads();
#pragma unroll
    for (int p = 0; p < 2; p++) {
        int i = tid + 256 * p;
        int t = i >> 3, c8 = i & 7;
        uh8 o0, o1, o2;
#pragma unroll
        for (int j = 0; j < 8; j++) {
            int c = c8 * 8 + j;
            float xv = bfu(su[c][t]);
            float n0 = fmaf(xv, ssc[0][c], ssh[0][c]);
            float n1 = fmaf(xv, ssc[1][c], ssh[1][c]);
            float n2 = fmaf(xv, ssc[2][c], ssh[2][c]);
            o0[j] = fbf(fmaxf(n0, 0.01f * n0));
            o1[j] = fbf(fmaxf(n1, 0.01f * n1));
            o2[j] = fbf(fmaxf(n2, 0.01f * n2));
        }
        long gi = (((long)b * F + f) * T + t0 + t) * 64 + c8 * 8;
        *(uh8*)&xn0[gi] = o0;
        *(uh8*)&xn1[gi] = o1;
        *(uh8*)&xn2[gi] = o2;
    }
}

// ---------------------------------------------------------------------------
// Pack weights fp32 -> bf16 fragments (layout proven round 10).
// Convs (lane-ordered, cb outermost): idx = (((cb*9+kk)*NCOT+ct)*64+l)*8+j
// conv0 @0 | conv1 @18432 | conv2 @46080 | o_w @119808 | sao_w @123904 |
// qkv_w @132096 (12288)   total 144384
// ---------------------------------------------------------------------------
__global__ __launch_bounds__(256) void prep_w_k(
    const float* __restrict__ w0, const float* __restrict__ w1,
    const float* __restrict__ w2, const float* __restrict__ ow,
    const float* __restrict__ sw, const float* __restrict__ qw,
    u16t* __restrict__ wp)
{
    int idx = blockIdx.x * 256 + threadIdx.x;
    if (idx >= 144384) return;
    if (idx < 119808) {
        int C_IN, C_OUT, e;
        const float* src;
        if (idx < 18432)      { C_IN = 64;  C_OUT = 32; src = w0; e = idx; }
        else if (idx < 46080) { C_IN = 96;  C_OUT = 32; src = w1; e = idx - 18432; }
        else                  { C_IN = 128; C_OUT = 64; src = w2; e = idx - 46080; }
        int NCOT = C_OUT / 16;
        int j  = e & 7;
        int l  = (e >> 3) & 63;
        int r  = e >> 9;
        int ct = r % NCOT;
        int r2 = r / NCOT;
        int kk = r2 % 9;
        int cb = r2 / 9;
        int co  = ct * 16 + (l & 15);
        int kin = cb * 32 + (l >> 4) * 8 + j;
        int kh = kk / 3, kw = kk % 3;
        wp[idx] = fbf(src[((co * C_IN + kin) * 3 + kh) * 3 + kw]);
    } else if (idx < 123904) {
        int e = idx - 119808;
        int ks = e & 31, co = (e >> 5) & 63, kb = e >> 11;
        wp[idx] = fbf(ow[co * 64 + kb * 32 + ks]);
    } else if (idx < 132096) {
        int e = idx - 123904;
        int ks = e & 31, co = (e >> 5) & 63, kb = e >> 11;
        wp[idx] = fbf(sw[co * 128 + kb * 32 + ks]);
    } else {
        int e = idx - 132096;
        int ks = e & 31, co = (e >> 5) % 192, kb = e / 6144;
        wp[idx] = fbf(qw[co * 64 + kb * 32 + ks]);
    }
}

// ---------------------------------------------------------------------------
// MFMA 3x3 conv on PRE-NORMALIZED bf16 inputs, FF=4 f-rows per block.
// Pure-copy LDS staging (no BN in hot loop); weights staged once per chunk
// serve 4 f-rows.  EPI: 0 = raw bf16 out; 1 = one normalized out (bn1 at
// channel bnoff+co); 2 = two normalized outs (bn1, bn2 at bnoff+co).
// ---------------------------------------------------------------------------
template<int C_IN, int C_OUT, int EPI>
__global__ __launch_bounds__(256) void conv3x3_ff4_k(
    const u16t* __restrict__ s0, const u16t* __restrict__ s1,
    const u16t* __restrict__ s2,
    const u16t* __restrict__ wseg, const float* __restrict__ wb,
    const float* __restrict__ g1, const float* __restrict__ b1,
    const float* __restrict__ m1, const float* __restrict__ v1,
    const float* __restrict__ g2, const float* __restrict__ b2,
    const float* __restrict__ m2, const float* __restrict__ v2,
    int bnoff, u16t* __restrict__ dst1, u16t* __restrict__ dst2)
{
    constexpr int F = 64, T = 512, TT = 64, FF = 4;
    constexpr int NCH  = C_IN / 32;
    constexpr int NCOT = C_OUT / 16;
    constexpr int WT = 9 * NCOT * 64;     // weight uh8 per chunk
    constexpr int XT = 6 * 66 * 4;        // 1584 x-tile uh8 per chunk

    __shared__ __align__(16) u16t s_x[6][66][40];
    __shared__ __align__(16) u16t s_w[WT * 8];

    const int tid = threadIdx.x;
    const int t0 = blockIdx.x * TT;
    const int f0 = blockIdx.y * FF;
    const int b  = blockIdx.z;

    const int l  = tid & 63;
    const int wv = tid >> 6;
    const int lr = l & 15;
    const int lq = l >> 4;

    f32x4 acc[4][NCOT];
#pragma unroll
    for (int i = 0; i < 4; i++)
#pragma unroll
        for (int j = 0; j < NCOT; j++) acc[i][j] = (f32x4){0.f, 0.f, 0.f, 0.f};

    for (int ch = 0; ch < NCH; ch++) {
        if (ch) __syncthreads();   // prev chunk consumed

        for (int idx = tid; idx < XT + WT; idx += 256) {
            if (idx < XT) {
                int oct = idx & 3;
                int row = idx >> 2;            // 0..395
                int fr = row / 66;
                int tp = row - fr * 66;
                int fi = f0 + fr - 1;
                int tg = t0 + tp - 1;
                int gc8 = ch * 4 + oct;
                uh8 v = (uh8)0;
                if ((unsigned)fi < (unsigned)F && (unsigned)tg < (unsigned)T) {
                    const u16t* sp; int coff, cw;
                    if (C_IN == 64 || gc8 < 8) { sp = s0; coff = gc8 * 8;        cw = 64; }
                    else if (gc8 < 12)         { sp = s1; coff = (gc8 - 8) * 8;  cw = 32; }
                    else                       { sp = s2; coff = (gc8 - 12) * 8; cw = 32; }
                    v = *(const uh8*)&sp[(((long)b * F + fi) * T + tg) * cw + coff];
                }
                *(uh8*)&s_x[fr][tp][oct * 8] = v;
            } else {
                int w = idx - XT;
                *(uh8*)&s_w[w * 8] = *(const uh8*)&wseg[((long)ch * WT + w) * 8];
            }
        }
        __syncthreads();

#pragma unroll
        for (int kk = 0; kk < 9; kk++) {
            const int kh = kk / 3, kw = kk % 3;
            bfrag A[NCOT];
#pragma unroll
            for (int ct = 0; ct < NCOT; ct++)
                A[ct] = *(const bfrag*)&s_w[((kk * NCOT + ct) * 64 + l) * 8];
#pragma unroll
            for (int ts = 0; ts < 4; ts++) {
                bfrag B = *(const bfrag*)&s_x[wv + kh][ts * 16 + lr + kw][lq * 8];
#pragma unroll
                for (int ct = 0; ct < NCOT; ct++)
                    acc[ts][ct] = __builtin_amdgcn_mfma_f32_16x16x32_bf16(
                        A[ct], B, acc[ts][ct], 0, 0, 0);
            }
        }
    }

    const int f = f0 + wv;
#pragma unroll
    for (int ct = 0; ct < NCOT; ct++) {
        const int co0 = ct * 16 + lq * 4;
        float4 bs = *(const float4*)&wb[co0];
        float sc1[4], sh1[4], sc2[4], sh2[4];
        if (EPI >= 1) {
#pragma unroll
            for (int j = 0; j < 4; j++) {
                int c = bnoff + co0 + j;
                float s = g1[c] * rsqrtf(v1[c] + 1e-5f);
                sc1[j] = s; sh1[j] = b1[c] - m1[c] * s;
            }
        }
        if (EPI == 2) {
#pragma unroll
            for (int j = 0; j < 4; j++) {
                int c = bnoff + co0 + j;
                float s = g2[c] * rsqrtf(v2[c] + 1e-5f);
                sc2[j] = s; sh2[j] = b2[c] - m2[c] * s;
            }
        }
#pragma unroll
        for (int ts = 0; ts < 4; ts++) {
            const int t = t0 + ts * 16 + lr;
            long ob = (((long)b * F + f) * T + t) * C_OUT + co0;
            float a[4];
            a[0] = acc[ts][ct][0] + bs.x;
            a[1] = acc[ts][ct][1] + bs.y;
            a[2] = acc[ts][ct][2] + bs.z;
            a[3] = acc[ts][ct][3] + bs.w;
            if (EPI == 0) {
                ushort4 pk;
                pk.x = fbf(a[0]); pk.y = fbf(a[1]);
                pk.z = fbf(a[2]); pk.w = fbf(a[3]);
                *(ushort4*)&dst1[ob] = pk;
            } else {
                ushort4 p1;
#pragma unroll
                for (int j = 0; j < 4; j++) {
                    float n = fmaf(a[j], sc1[j], sh1[j]);
                    ((u16t*)&p1)[j] = fbf(fmaxf(n, 0.01f * n));
                }
                *(ushort4*)&dst1[ob] = p1;
                if (EPI == 2) {
                    ushort4 p2;
#pragma unroll
                    for (int j = 0; j < 4; j++) {
                        float n = fmaf(a[j], sc2[j], sh2[j]);
                        ((u16t*)&p2)[j] = fbf(fmaxf(n, 0.01f * n));
                    }
                    *(ushort4*)&dst2[ob] = p2;
                }
            }
        }
    }
}

// ---------------------------------------------------------------------------
// MFMA qkv projection (proven round 9/10).
// ---------------------------------------------------------------------------
__global__ __launch_bounds__(256) void qkv_mfma_k(
    const u16t* __restrict__ ybf, const u16t* __restrict__ wq,
    const float* __restrict__ qbias,
    u16t* __restrict__ q_t, u16t* __restrict__ k_t, u16t* __restrict__ v_t)
{
    constexpr int F = 64, T = 512;
    __shared__ __align__(16) u16t s_y[64][72];
    const int tid = threadIdx.x;
    const int t0 = blockIdx.x * 64;
    const int f = blockIdx.y, b = blockIdx.z;
    const long bf = (long)b * F + f;

    for (int i = tid; i < 512; i += 256) {
        int tt = i >> 3, c0 = (i & 7) * 8;
        *(uh8*)&s_y[tt][c0] = *(const uh8*)&ybf[(bf * T + t0 + tt) * 64 + c0];
    }
    __syncthreads();

    const int l = tid & 63, wv = tid >> 6;
    const int lr = l & 15, lq = l >> 4;
    const int tb = wv * 16 + lr;

    bfrag B0 = *(const bfrag*)&s_y[tb][lq * 8];
    bfrag B1 = *(const bfrag*)&s_y[tb][32 + lq * 8];

    f32x4 acc[12];
#pragma unroll
    for (int i = 0; i < 12; i++) acc[i] = (f32x4){0.f, 0.f, 0.f, 0.f};
#pragma unroll
    for (int ct = 0; ct < 12; ct++) {
        bfrag A0 = *(const bfrag*)&wq[(ct * 16 + lr) * 32 + lq * 8];
        acc[ct] = __builtin_amdgcn_mfma_f32_16x16x32_bf16(A0, B0, acc[ct], 0, 0, 0);
    }
#pragma unroll
    for (int ct = 0; ct < 12; ct++) {
        bfrag A1 = *(const bfrag*)&wq[(192 + ct * 16 + lr) * 32 + lq * 8];
        acc[ct] = __builtin_amdgcn_mfma_f32_16x16x32_bf16(A1, B1, acc[ct], 0, 0, 0);
    }

    const int t = t0 + tb;
#pragma unroll
    for (int ct = 0; ct < 12; ct++) {
        int co0 = ct * 16 + lq * 4;
        float4 bi = *(const float4*)&qbias[co0];
        float a0 = acc[ct][0] + bi.x, a1 = acc[ct][1] + bi.y;
        float a2 = acc[ct][2] + bi.z, a3 = acc[ct][3] + bi.w;
        if (co0 < 64) {
            ushort4 pk;
            pk.x = fbf(a0 * 0.25f); pk.y = fbf(a1 * 0.25f);
            pk.z = fbf(a2 * 0.25f); pk.w = fbf(a3 * 0.25f);
            *(ushort4*)&q_t[(bf * T + t) * 64 + co0] = pk;
        } else if (co0 < 128) {
            int hh = (co0 - 64) >> 4, d0 = (co0 - 64) & 15;
            ushort4 pk;
            pk.x = fbf(a0); pk.y = fbf(a1); pk.z = fbf(a2); pk.w = fbf(a3);
            *(ushort4*)&k_t[((bf * 4 + hh) * T + t) * 16 + d0] = pk;
        } else {
            int hh = (co0 - 128) >> 4, d0 = (co0 - 128) & 15;
            long vb = (bf * 4 + hh) * 16;
            v_t[(vb + d0 + 0) * T + t] = fbf(a0);
            v_t[(vb + d0 + 1) * T + t] = fbf(a1);
            v_t[(vb + d0 + 2) * T + t] = fbf(a2);
            v_t[(vb + d0 + 3) * T + t] = fbf(a3);
        }
    }
}

// ---------------------------------------------------------------------------
// MFMA banded attention (proven round 9/10).  ob aliases q_t in-place.
// ---------------------------------------------------------------------------
__global__ __launch_bounds__(256) void attn_mfma_k(
    const u16t* __restrict__ qt, const u16t* __restrict__ kt_,
    const u16t* __restrict__ vt, u16t* __restrict__ ob)
{
    constexpr int T = 512, F = 64;
    const int qc = blockIdx.x & 7;
    const int h  = blockIdx.x >> 3;
    const int f = blockIdx.y, b = blockIdx.z;
    const int qb0 = qc * 64;
    const int tid = threadIdx.x;
    const long bf = (long)b * F + f;
    const long kvb = bf * 4 + h;

    __shared__ __align__(16) u16t s_k[192][24];
    __shared__ __align__(16) u16t s_v[16][216];
    __shared__ __align__(16) u16t s_p[4][16][168];
    __shared__ __align__(16) u16t s_zero[8];

    if (tid < 8) s_zero[tid] = 0;

    for (int idx = tid; idx < 384; idx += 256) {
        int kk = idx >> 1, hv = idx & 1;
        int p = qb0 - 64 + kk;
        uh8 v = (uh8)0;
        if ((unsigned)p < (unsigned)T)
            v = *(const uh8*)&kt_[(kvb * T + p) * 16 + hv * 8];
        *(uh8*)&s_k[kk][hv * 8] = v;
    }
    for (int idx = tid; idx < 432; idx += 256) {
        int d = idx / 27, c8 = idx % 27;
        int kk0 = c8 * 8;
        int p0 = qb0 - 64 + kk0;
        uh8 v = (uh8)0;
        if (p0 >= 0 && p0 + 7 < T) {
            v = *(const uh8*)&vt[(kvb * 16 + d) * T + p0];
        } else {
#pragma unroll
            for (int j = 0; j < 8; j++) {
                int p = p0 + j;
                v[j] = ((unsigned)p < (unsigned)T)
                     ? vt[(kvb * 16 + d) * T + p] : (u16t)0;
            }
        }
        *(uh8*)&s_v[d][kk0] = v;
    }
    __syncthreads();

    const int l  = tid & 63;
    const int wv = tid >> 6;
    const int lr = l & 15;
    const int lq = l >> 4;
    const int qt0 = qb0 + wv * 16;

    bfrag Bq = (bfrag)0;
    if (lq < 2)
        Bq = *(const bfrag*)&qt[(bf * T + qt0 + lr) * 64 + h * 16 + lq * 8];

    f32x4 sf[9];
#pragma unroll
    for (int kti = 0; kti < 9; kti++) {
        const u16t* ap = (lq < 2) ? &s_k[wv * 16 + kti * 16 + lr][lq * 8]
                                  : &s_zero[0];
        bfrag A = *(const bfrag*)ap;
        sf[kti] = __builtin_amdgcn_mfma_f32_16x16x32_bf16(
            A, Bq, (f32x4){0.f, 0.f, 0.f, 0.f}, 0, 0, 0);
    }

    float m = -3.0e38f;
#pragma unroll
    for (int kti = 0; kti < 9; kti++) {
#pragma unroll
        for (int j = 0; j < 4; j++) {
            int rk = kti * 16 + lq * 4 + j;
            int dq = rk - lr;
            int p  = qt0 - 64 + rk;
            float s = sf[kti][j];
            s = (dq >= 0 && dq <= 128 && p < T) ? s : -1.0e30f;
            sf[kti][j] = s;
            m = fmaxf(m, s);
        }
    }
    m = fmaxf(m, __shfl_xor(m, 16));
    m = fmaxf(m, __shfl_xor(m, 32));

    float lsum = 0.f;
#pragma unroll
    for (int kti = 0; kti < 9; kti++) {
#pragma unroll
        for (int j = 0; j < 4; j++) {
            float e = __expf(sf[kti][j] - m);
            sf[kti][j] = e;
            lsum += e;
        }
    }
    lsum += __shfl_xor(lsum, 16);
    lsum += __shfl_xor(lsum, 32);

#pragma unroll
    for (int kti = 0; kti < 9; kti++) {
        ushort4 pk;
        pk.x = fbf(sf[kti][0]); pk.y = fbf(sf[kti][1]);
        pk.z = fbf(sf[kti][2]); pk.w = fbf(sf[kti][3]);
        *(ushort4*)&s_p[wv][lr][kti * 16 + lq * 4] = pk;
    }
    {
        ushort4 z; z.x = 0; z.y = 0; z.z = 0; z.w = 0;
        *(ushort4*)&s_p[wv][lr][144 + lq * 4] = z;
    }
    __syncthreads();

    f32x4 oa = (f32x4){0.f, 0.f, 0.f, 0.f};
#pragma unroll
    for (int kc = 0; kc < 5; kc++) {
        bfrag Av = *(const bfrag*)&s_v[lr][wv * 16 + kc * 32 + lq * 8];
        bfrag Bp = *(const bfrag*)&s_p[wv][lr][kc * 32 + lq * 8];
        oa = __builtin_amdgcn_mfma_f32_16x16x32_bf16(Av, Bp, oa, 0, 0, 0);
    }
    const float inv = 1.0f / lsum;
    ushort4 ov;
    ov.x = fbf(oa[0] * inv); ov.y = fbf(oa[1] * inv);
    ov.z = fbf(oa[2] * inv); ov.w = fbf(oa[3] * inv);
    *(ushort4*)&ob[(bf * T + qt0 + lr) * 64 + h * 16 + lq * 4] = ov;
}

// ---------------------------------------------------------------------------
// MFMA fused o-projection + BN + LeakyReLU + final conv1x1 (proven round 9).
// ---------------------------------------------------------------------------
__global__ __launch_bounds__(256) void final_mfma_k(
    const u16t* __restrict__ ob, const u16t* __restrict__ yb,
    const u16t* __restrict__ wo, const float* __restrict__ obias,
    const float* __restrict__ sg, const float* __restrict__ sb,
    const float* __restrict__ sm, const float* __restrict__ sv,
    const u16t* __restrict__ wsao, const float* __restrict__ swb,
    float* __restrict__ out)
{
    constexpr int F = 64, T = 512, TT = 64, P = 72;
    __shared__ __align__(16) u16t s_ob[64][P];
    __shared__ __align__(16) u16t s_y2[64][P];
    __shared__ __align__(16) u16t s_att[64][P];
    __shared__ float s_sc[128], s_sh[128];

    const int tid = threadIdx.x;
    const int t0 = blockIdx.x * TT;
    const int f = blockIdx.y, b = blockIdx.z;

    if (tid < 128) {
        float sc = sg[tid] * rsqrtf(sv[tid] + 1e-5f);
        s_sc[tid] = sc;
        s_sh[tid] = sb[tid] - sm[tid] * sc;
    }
    __syncthreads();

    for (int i = tid; i < 512; i += 256) {
        int tt = i >> 3, c0 = (i & 7) * 8;
        long gi = (((long)b * F + f) * T + t0 + tt) * 64 + c0;
        *(uh8*)&s_ob[tt][c0] = *(const uh8*)&ob[gi];
        uh8 raw = *(const uh8*)&yb[gi];
        uh8 v;
#pragma unroll
        for (int j = 0; j < 8; j++) {
            float xv = bfu(raw[j]);
            float xn = fmaf(xv, s_sc[c0 + j], s_sh[c0 + j]);
            v[j] = fbf(fmaxf(xn, 0.01f * xn));
        }
        *(uh8*)&s_y2[tt][c0] = v;
    }
    __syncthreads();

    const int l  = tid & 63;
    const int wv = tid >> 6;
    const int lr = l & 15;
    const int lq = l >> 4;
    const int tbase = wv * 16 + lr;
    const int cbase = lq * 8;

    f32x4 acc1[4];
#pragma unroll
    for (int i = 0; i < 4; i++) acc1[i] = (f32x4){0.f, 0.f, 0.f, 0.f};
#pragma unroll
    for (int kb = 0; kb < 2; kb++) {
        bfrag B = *(const bfrag*)&s_ob[tbase][kb * 32 + cbase];
#pragma unroll
        for (int ct = 0; ct < 4; ct++) {
            bfrag A = *(const bfrag*)&wo[(kb * 64 + ct * 16 + lr) * 32 + lq * 8];
            acc1[ct] = __builtin_amdgcn_mfma_f32_16x16x32_bf16(A, B, acc1[ct], 0, 0, 0);
        }
    }
#pragma unroll
    for (int ct = 0; ct < 4; ct++) {
        int co = ct * 16 + lq * 4;
        float4 bi = *(const float4*)&obias[co];
#pragma unroll
        for (int j = 0; j < 4; j++) {
            float a = acc1[ct][j] + ((j == 0) ? bi.x : (j == 1) ? bi.y : (j == 2) ? bi.z : bi.w);
            int cg = 64 + co + j;
            float xn = fmaf(a, s_sc[cg], s_sh[cg]);
            s_att[tbase][co + j] = fbf(fmaxf(xn, 0.01f * xn));
        }
    }
    __syncthreads();

    f32x4 acc2[4];
#pragma unroll
    for (int i = 0; i < 4; i++) acc2[i] = (f32x4){0.f, 0.f, 0.f, 0.f};
#pragma unroll
    for (int kb = 0; kb < 4; kb++) {
        bfrag B = (kb < 2) ? *(const bfrag*)&s_y2[tbase][kb * 32 + cbase]
                           : *(const bfrag*)&s_att[tbase][(kb - 2) * 32 + cbase];
#pragma unroll
        for (int ct = 0; ct < 4; ct++) {
            bfrag A = *(const bfrag*)&wsao[(kb * 64 + ct * 16 + lr) * 32 + lq * 8];
            acc2[ct] = __builtin_amdgcn_mfma_f32_16x16x32_bf16(A, B, acc2[ct], 0, 0, 0);
        }
    }
    const int t = t0 + wv * 16 + lr;
#pragma unroll
    for (int ct = 0; ct < 4; ct++) {
        int co0 = ct * 16 + lq * 4;
        float4 bs = *(const float4*)&swb[co0];
#pragma unroll
        for (int j = 0; j < 4; j++) {
            float bv = (j == 0) ? bs.x : (j == 1) ? bs.y : (j == 2) ? bs.z : bs.w;
            out[(((long)b * 64 + co0 + j) * F + f) * T + t] = acc2[ct][j] + bv;
        }
    }
}

// ---------------------------------------------------------------------------
extern "C" void kernel_launch(void* const* d_in, const int* in_sizes, int n_in,
                              void* d_out, int out_size, void* d_ws, size_t ws_size,
                              hipStream_t stream)
{
    (void)in_sizes; (void)n_in; (void)out_size; (void)ws_size;

    const float* x      = (const float*)d_in[0];
    const float* bd0_g  = (const float*)d_in[1];
    const float* bd0_b  = (const float*)d_in[2];
    const float* bd0_m  = (const float*)d_in[3];
    const float* bd0_v  = (const float*)d_in[4];
    const float* bd0_w  = (const float*)d_in[5];
    const float* bd0_wb = (const float*)d_in[6];
    const float* bd1_g  = (const float*)d_in[7];
    const float* bd1_b  = (const float*)d_in[8];
    const float* bd1_m  = (const float*)d_in[9];
    const float* bd1_v  = (const float*)d_in[10];
    const float* bd1_w  = (const float*)d_in[11];
    const float* bd1_wb = (const float*)d_in[12];
    const float* bdo_g  = (const float*)d_in[13];
    const float* bdo_b  = (const float*)d_in[14];
    const float* bdo_m  = (const float*)d_in[15];
    const float* bdo_v  = (const float*)d_in[16];
    const float* bdo_w  = (const float*)d_in[17];
    const float* bdo_wb = (const float*)d_in[18];
    const float* qkv_w  = (const float*)d_in[19];
    const float* qkv_b  = (const float*)d_in[20];
    const float* o_w    = (const float*)d_in[21];
    const float* o_b    = (const float*)d_in[22];
    const float* sao_g  = (const float*)d_in[23];
    const float* sao_b  = (const float*)d_in[24];
    const float* sao_m  = (const float*)d_in[25];
    const float* sao_v  = (const float*)d_in[26];
    const float* sao_w  = (const float*)d_in[27];
    const float* sao_wb = (const float*)d_in[28];

    char* ws = (char*)d_ws;
    // ws map (bytes), peak 75.8MB (ws >= 83.9MB proven by rounds 2/3):
    //   [0.0 , 16.8M)  xn0  -> ybf (conv2 out; xn0 dead after conv0)
    //   [16.8, 33.6M)  xn1  -> q_t (qkv out; xn1 dead) -> obf (in-place)
    //   [33.6, 50.3M)  xn2  -> k_t (xn2 dead after conv2)
    //   [50.3, 58.7M)  a0n1 \ -> v_t [50.3,67.1) (a0n* dead after conv1/2)
    //   [58.7, 67.1M)  a0n2 /
    //   [67.1, 75.5M)  a1n2
    //   [75.5, 75.8M)  wpack bf16 (144384 entries)
    u16t* xn0  = (u16t*)(ws);
    u16t* xn1  = (u16t*)(ws + 16777216);
    u16t* xn2  = (u16t*)(ws + 33554432);
    u16t* a0n1 = (u16t*)(ws + 50331648);
    u16t* a0n2 = (u16t*)(ws + 58720256);
    u16t* a1n2 = (u16t*)(ws + 67108864);
    u16t* ybf  = xn0;
    u16t* q_t  = xn1;
    u16t* k_t  = xn2;
    u16t* v_t  = a0n1;
    u16t* obf  = q_t;                      // in-place alias (proven)
    u16t* wpk  = (u16t*)(ws + 75497472);

    dim3 blk(256);
    dim3 gprep(8, 64, 4);   // T/64, F, B
    dim3 gconv(8, 16, 4);   // T/64, F/4, B

    hipLaunchKernelGGL(prep_x3_k, gprep, blk, 0, stream, x,
        bd0_g, bd0_b, bd0_m, bd0_v, bd1_g, bd1_b, bd1_m, bd1_v,
        bdo_g, bdo_b, bdo_m, bdo_v, xn0, xn1, xn2);
    hipLaunchKernelGGL(prep_w_k, dim3(564), blk, 0, stream,
        bd0_w, bd1_w, bdo_w, o_w, sao_w, qkv_w, wpk);
    hipLaunchKernelGGL((conv3x3_ff4_k<64, 32, 2>), gconv, blk, 0, stream,
        xn0, nullptr, nullptr, wpk, bd0_wb,
        bd1_g, bd1_b, bd1_m, bd1_v, bdo_g, bdo_b, bdo_m, bdo_v,
        64, a0n1, a0n2);
    hipLaunchKernelGGL((conv3x3_ff4_k<96, 32, 1>), gconv, blk, 0, stream,
        xn1, a0n1, nullptr, wpk + 18432, bd1_wb,
        bdo_g, bdo_b, bdo_m, bdo_v, nullptr, nullptr, nullptr, nullptr,
        96, a1n2, nullptr);
    hipLaunchKernelGGL((conv3x3_ff4_k<128, 64, 0>), gconv, blk, 0, stream,
        xn2, a0n2, a1n2, wpk + 46080, bdo_wb,
        nullptr, nullptr, nullptr, nullptr, nullptr, nullptr, nullptr, nullptr,
        0, ybf, nullptr);
    hipLaunchKernelGGL(qkv_mfma_k, gprep, blk, 0, stream,
        ybf, wpk + 132096, qkv_b, q_t, k_t, v_t);
    hipLaunchKernelGGL(attn_mfma_k, dim3(32, 64, 4), blk, 0, stream,
        q_t, k_t, v_t, obf);
    hipLaunchKernelGGL(final_mfma_k, gprep, blk, 0, stream,
        obf, ybf, wpk + 119808, o_b, sao_g, sao_b, sao_m, sao_v,
        wpk + 123904, sao_wb, (float*)d_out);
}

// Round 12
// 177.171 us; speedup vs baseline: 7.2454x; 1.0295x over previous
//
#include <hip/hip_runtime.h>
#include <hip/hip_bf16.h>

typedef unsigned short u16t;
typedef __attribute__((ext_vector_type(8))) short bfrag;      // 8 bf16 bits
typedef __attribute__((ext_vector_type(4))) float f32x4;      // MFMA acc
typedef __attribute__((ext_vector_type(8))) unsigned short uh8;

__device__ __forceinline__ float bfu(u16t u) {
    union { unsigned int i; float f; } c;
    c.i = ((unsigned int)u) << 16;
    return c.f;
}
__device__ __forceinline__ u16t fbf(float f) {
    __hip_bfloat16 h = __float2bfloat16(f);
    return *reinterpret_cast<u16t*>(&h);
}

// ---------------------------------------------------------------------------
// x [b][64c][64f][512t] fp32 -> three normalized bf16 copies in [b][f][t][64]:
// xn0 = lrelu(bn_bd0(x)), xn1 = lrelu(bn_bd1(x)), xn2 = lrelu(bn_bdo(x))
// ---------------------------------------------------------------------------
__global__ __launch_bounds__(256) void prep_x3_k(
    const float* __restrict__ x,
    const float* __restrict__ g0, const float* __restrict__ b0,
    const float* __restrict__ m0, const float* __restrict__ v0,
    const float* __restrict__ g1, const float* __restrict__ b1,
    const float* __restrict__ m1, const float* __restrict__ v1,
    const float* __restrict__ g2, const float* __restrict__ b2,
    const float* __restrict__ m2, const float* __restrict__ v2,
    u16t* __restrict__ xn0, u16t* __restrict__ xn1, u16t* __restrict__ xn2)
{
    constexpr int F = 64, T = 512;
    __shared__ u16t su[64][74];
    __shared__ float ssc[3][64], ssh[3][64];
    const int tid = threadIdx.x;
    const int t0 = blockIdx.x * 64;
    const int f = blockIdx.y, b = blockIdx.z;

    if (tid < 64) {
        int c = tid;
        float s;
        s = g0[c] * rsqrtf(v0[c] + 1e-5f); ssc[0][c] = s; ssh[0][c] = b0[c] - m0[c] * s;
        s = g1[c] * rsqrtf(v1[c] + 1e-5f); ssc[1][c] = s; ssh[1][c] = b1[c] - m1[c] * s;
        s = g2[c] * rsqrtf(v2[c] + 1e-5f); ssc[2][c] = s; ssh[2][c] = b2[c] - m2[c] * s;
    }
#pragma unroll
    for (int p = 0; p < 16; p++) {
        int i = tid + 256 * p;
        int c = i >> 6, t = i & 63;
        su[c][t] = fbf(x[(((long)b * 64 + c) * F + f) * T + t0 + t]);
    }
    __syncthreads();
#pragma unroll
    for (int p = 0; p < 2; p++) {
        int i = tid + 256 * p;
        int t = i >> 3, c8 = i & 7;
        uh8 o0, o1, o2;
#pragma unroll
        for (int j = 0; j < 8; j++) {
            int c = c8 * 8 + j;
            float xv = bfu(su[c][t]);
            float n0 = fmaf(xv, ssc[0][c], ssh[0][c]);
            float n1 = fmaf(xv, ssc[1][c], ssh[1][c]);
            float n2 = fmaf(xv, ssc[2][c], ssh[2][c]);
            o0[j] = fbf(fmaxf(n0, 0.01f * n0));
            o1[j] = fbf(fmaxf(n1, 0.01f * n1));
            o2[j] = fbf(fmaxf(n2, 0.01f * n2));
        }
        long gi = (((long)b * F + f) * T + t0 + t) * 64 + c8 * 8;
        *(uh8*)&xn0[gi] = o0;
        *(uh8*)&xn1[gi] = o1;
        *(uh8*)&xn2[gi] = o2;
    }
}

// ---------------------------------------------------------------------------
// Pack weights fp32 -> bf16 fragments (layout proven round 10).
// Convs (lane-ordered, cb outermost): idx = (((cb*9+kk)*NCOT+ct)*64+l)*8+j
// conv0 @0 | conv1 @18432 | conv2 @46080 | o_w @119808 | sao_w @123904 |
// qkv_w @132096 (12288)   total 144384
// ---------------------------------------------------------------------------
__global__ __launch_bounds__(256) void prep_w_k(
    const float* __restrict__ w0, const float* __restrict__ w1,
    const float* __restrict__ w2, const float* __restrict__ ow,
    const float* __restrict__ sw, const float* __restrict__ qw,
    u16t* __restrict__ wp)
{
    int idx = blockIdx.x * 256 + threadIdx.x;
    if (idx >= 144384) return;
    if (idx < 119808) {
        int C_IN, C_OUT, e;
        const float* src;
        if (idx < 18432)      { C_IN = 64;  C_OUT = 32; src = w0; e = idx; }
        else if (idx < 46080) { C_IN = 96;  C_OUT = 32; src = w1; e = idx - 18432; }
        else                  { C_IN = 128; C_OUT = 64; src = w2; e = idx - 46080; }
        int NCOT = C_OUT / 16;
        int j  = e & 7;
        int l  = (e >> 3) & 63;
        int r  = e >> 9;
        int ct = r % NCOT;
        int r2 = r / NCOT;
        int kk = r2 % 9;
        int cb = r2 / 9;
        int co  = ct * 16 + (l & 15);
        int kin = cb * 32 + (l >> 4) * 8 + j;
        int kh = kk / 3, kw = kk % 3;
        wp[idx] = fbf(src[((co * C_IN + kin) * 3 + kh) * 3 + kw]);
    } else if (idx < 123904) {
        int e = idx - 119808;
        int ks = e & 31, co = (e >> 5) & 63, kb = e >> 11;
        wp[idx] = fbf(ow[co * 64 + kb * 32 + ks]);
    } else if (idx < 132096) {
        int e = idx - 123904;
        int ks = e & 31, co = (e >> 5) & 63, kb = e >> 11;
        wp[idx] = fbf(sw[co * 128 + kb * 32 + ks]);
    } else {
        int e = idx - 132096;
        int ks = e & 31, co = (e >> 5) % 192, kb = e / 6144;
        wp[idx] = fbf(qw[co * 64 + kb * 32 + ks]);
    }
}

// ---------------------------------------------------------------------------
// MFMA 3x3 conv on PRE-NORMALIZED bf16 inputs, FF=4 f-rows per block
// (proven round 11).
// ---------------------------------------------------------------------------
template<int C_IN, int C_OUT, int EPI>
__global__ __launch_bounds__(256) void conv3x3_ff4_k(
    const u16t* __restrict__ s0, const u16t* __restrict__ s1,
    const u16t* __restrict__ s2,
    const u16t* __restrict__ wseg, const float* __restrict__ wb,
    const float* __restrict__ g1, const float* __restrict__ b1,
    const float* __restrict__ m1, const float* __restrict__ v1,
    const float* __restrict__ g2, const float* __restrict__ b2,
    const float* __restrict__ m2, const float* __restrict__ v2,
    int bnoff, u16t* __restrict__ dst1, u16t* __restrict__ dst2)
{
    constexpr int F = 64, T = 512, TT = 64, FF = 4;
    constexpr int NCH  = C_IN / 32;
    constexpr int NCOT = C_OUT / 16;
    constexpr int WT = 9 * NCOT * 64;
    constexpr int XT = 6 * 66 * 4;

    __shared__ __align__(16) u16t s_x[6][66][40];
    __shared__ __align__(16) u16t s_w[WT * 8];

    const int tid = threadIdx.x;
    const int t0 = blockIdx.x * TT;
    const int f0 = blockIdx.y * FF;
    const int b  = blockIdx.z;

    const int l  = tid & 63;
    const int wv = tid >> 6;
    const int lr = l & 15;
    const int lq = l >> 4;

    f32x4 acc[4][NCOT];
#pragma unroll
    for (int i = 0; i < 4; i++)
#pragma unroll
        for (int j = 0; j < NCOT; j++) acc[i][j] = (f32x4){0.f, 0.f, 0.f, 0.f};

    for (int ch = 0; ch < NCH; ch++) {
        if (ch) __syncthreads();

        for (int idx = tid; idx < XT + WT; idx += 256) {
            if (idx < XT) {
                int oct = idx & 3;
                int row = idx >> 2;
                int fr = row / 66;
                int tp = row - fr * 66;
                int fi = f0 + fr - 1;
                int tg = t0 + tp - 1;
                int gc8 = ch * 4 + oct;
                uh8 v = (uh8)0;
                if ((unsigned)fi < (unsigned)F && (unsigned)tg < (unsigned)T) {
                    const u16t* sp; int coff, cw;
                    if (C_IN == 64 || gc8 < 8) { sp = s0; coff = gc8 * 8;        cw = 64; }
                    else if (gc8 < 12)         { sp = s1; coff = (gc8 - 8) * 8;  cw = 32; }
                    else                       { sp = s2; coff = (gc8 - 12) * 8; cw = 32; }
                    v = *(const uh8*)&sp[(((long)b * F + fi) * T + tg) * cw + coff];
                }
                *(uh8*)&s_x[fr][tp][oct * 8] = v;
            } else {
                int w = idx - XT;
                *(uh8*)&s_w[w * 8] = *(const uh8*)&wseg[((long)ch * WT + w) * 8];
            }
        }
        __syncthreads();

#pragma unroll
        for (int kk = 0; kk < 9; kk++) {
            const int kh = kk / 3, kw = kk % 3;
            bfrag A[NCOT];
#pragma unroll
            for (int ct = 0; ct < NCOT; ct++)
                A[ct] = *(const bfrag*)&s_w[((kk * NCOT + ct) * 64 + l) * 8];
#pragma unroll
            for (int ts = 0; ts < 4; ts++) {
                bfrag B = *(const bfrag*)&s_x[wv + kh][ts * 16 + lr + kw][lq * 8];
#pragma unroll
                for (int ct = 0; ct < NCOT; ct++)
                    acc[ts][ct] = __builtin_amdgcn_mfma_f32_16x16x32_bf16(
                        A[ct], B, acc[ts][ct], 0, 0, 0);
            }
        }
    }

    const int f = f0 + wv;
#pragma unroll
    for (int ct = 0; ct < NCOT; ct++) {
        const int co0 = ct * 16 + lq * 4;
        float4 bs = *(const float4*)&wb[co0];
        float sc1[4], sh1[4], sc2[4], sh2[4];
        if (EPI >= 1) {
#pragma unroll
            for (int j = 0; j < 4; j++) {
                int c = bnoff + co0 + j;
                float s = g1[c] * rsqrtf(v1[c] + 1e-5f);
                sc1[j] = s; sh1[j] = b1[c] - m1[c] * s;
            }
        }
        if (EPI == 2) {
#pragma unroll
            for (int j = 0; j < 4; j++) {
                int c = bnoff + co0 + j;
                float s = g2[c] * rsqrtf(v2[c] + 1e-5f);
                sc2[j] = s; sh2[j] = b2[c] - m2[c] * s;
            }
        }
#pragma unroll
        for (int ts = 0; ts < 4; ts++) {
            const int t = t0 + ts * 16 + lr;
            long ob = (((long)b * F + f) * T + t) * C_OUT + co0;
            float a[4];
            a[0] = acc[ts][ct][0] + bs.x;
            a[1] = acc[ts][ct][1] + bs.y;
            a[2] = acc[ts][ct][2] + bs.z;
            a[3] = acc[ts][ct][3] + bs.w;
            if (EPI == 0) {
                ushort4 pk;
                pk.x = fbf(a[0]); pk.y = fbf(a[1]);
                pk.z = fbf(a[2]); pk.w = fbf(a[3]);
                *(ushort4*)&dst1[ob] = pk;
            } else {
                ushort4 p1;
#pragma unroll
                for (int j = 0; j < 4; j++) {
                    float n = fmaf(a[j], sc1[j], sh1[j]);
                    ((u16t*)&p1)[j] = fbf(fmaxf(n, 0.01f * n));
                }
                *(ushort4*)&dst1[ob] = p1;
                if (EPI == 2) {
                    ushort4 p2;
#pragma unroll
                    for (int j = 0; j < 4; j++) {
                        float n = fmaf(a[j], sc2[j], sh2[j]);
                        ((u16t*)&p2)[j] = fbf(fmaxf(n, 0.01f * n));
                    }
                    *(ushort4*)&dst2[ob] = p2;
                }
            }
        }
    }
}

// ---------------------------------------------------------------------------
// MFMA qkv projection.  Q now scaled by 0.25*log2(e) so attention can use
// exp2 directly (softmax in log2 domain; mathematically identical).
// ---------------------------------------------------------------------------
__global__ __launch_bounds__(256) void qkv_mfma_k(
    const u16t* __restrict__ ybf, const u16t* __restrict__ wq,
    const float* __restrict__ qbias,
    u16t* __restrict__ q_t, u16t* __restrict__ k_t, u16t* __restrict__ v_t)
{
    constexpr int F = 64, T = 512;
    __shared__ __align__(16) u16t s_y[64][72];
    const int tid = threadIdx.x;
    const int t0 = blockIdx.x * 64;
    const int f = blockIdx.y, b = blockIdx.z;
    const long bf = (long)b * F + f;

    for (int i = tid; i < 512; i += 256) {
        int tt = i >> 3, c0 = (i & 7) * 8;
        *(uh8*)&s_y[tt][c0] = *(const uh8*)&ybf[(bf * T + t0 + tt) * 64 + c0];
    }
    __syncthreads();

    const int l = tid & 63, wv = tid >> 6;
    const int lr = l & 15, lq = l >> 4;
    const int tb = wv * 16 + lr;

    bfrag B0 = *(const bfrag*)&s_y[tb][lq * 8];
    bfrag B1 = *(const bfrag*)&s_y[tb][32 + lq * 8];

    f32x4 acc[12];
#pragma unroll
    for (int i = 0; i < 12; i++) acc[i] = (f32x4){0.f, 0.f, 0.f, 0.f};
#pragma unroll
    for (int ct = 0; ct < 12; ct++) {
        bfrag A0 = *(const bfrag*)&wq[(ct * 16 + lr) * 32 + lq * 8];
        acc[ct] = __builtin_amdgcn_mfma_f32_16x16x32_bf16(A0, B0, acc[ct], 0, 0, 0);
    }
#pragma unroll
    for (int ct = 0; ct < 12; ct++) {
        bfrag A1 = *(const bfrag*)&wq[(192 + ct * 16 + lr) * 32 + lq * 8];
        acc[ct] = __builtin_amdgcn_mfma_f32_16x16x32_bf16(A1, B1, acc[ct], 0, 0, 0);
    }

    const float QS = 0.25f * 1.44269504088896f;   // fold 1/sqrt(16) * log2(e)
    const int t = t0 + tb;
#pragma unroll
    for (int ct = 0; ct < 12; ct++) {
        int co0 = ct * 16 + lq * 4;
        float4 bi = *(const float4*)&qbias[co0];
        float a0 = acc[ct][0] + bi.x, a1 = acc[ct][1] + bi.y;
        float a2 = acc[ct][2] + bi.z, a3 = acc[ct][3] + bi.w;
        if (co0 < 64) {
            ushort4 pk;
            pk.x = fbf(a0 * QS); pk.y = fbf(a1 * QS);
            pk.z = fbf(a2 * QS); pk.w = fbf(a3 * QS);
            *(ushort4*)&q_t[(bf * T + t) * 64 + co0] = pk;
        } else if (co0 < 128) {
            int hh = (co0 - 64) >> 4, d0 = (co0 - 64) & 15;
            ushort4 pk;
            pk.x = fbf(a0); pk.y = fbf(a1); pk.z = fbf(a2); pk.w = fbf(a3);
            *(ushort4*)&k_t[((bf * 4 + hh) * T + t) * 16 + d0] = pk;
        } else {
            int hh = (co0 - 128) >> 4, d0 = (co0 - 128) & 15;
            long vb = (bf * 4 + hh) * 16;
            v_t[(vb + d0 + 0) * T + t] = fbf(a0);
            v_t[(vb + d0 + 1) * T + t] = fbf(a1);
            v_t[(vb + d0 + 2) * T + t] = fbf(a2);
            v_t[(vb + d0 + 3) * T + t] = fbf(a3);
        }
    }
}

// ---------------------------------------------------------------------------
// MFMA banded attention, stage-free: K/V/Q fragments loaded DIRECTLY from
// global (16B per lane; V frag base p0 is always a multiple of 8 so OOB
// never straddles a fragment -> whole-frag cndmask zeroing).  Masks
// specialized per q-chunk: middle kti 1..7 provably in-band; qc==0 zeroes
// phantom K/V (score 0, value 0 - included); qc==7 keeps the full mask.
// Softmax via exp2 (Q pre-scaled by log2 e).  LDS: s_p only (21.5 KB).
// ob aliases q_t in-place (proven).
// ---------------------------------------------------------------------------
__global__ __launch_bounds__(256) void attn_mfma_k(
    const u16t* __restrict__ qt, const u16t* __restrict__ kt_,
    const u16t* __restrict__ vt, u16t* __restrict__ ob)
{
    constexpr int T = 512, F = 64;
    const int qc = blockIdx.x & 7;
    const int h  = blockIdx.x >> 3;
    const int f = blockIdx.y, b = blockIdx.z;
    const int qb0 = qc * 64;
    const int tid = threadIdx.x;
    const long bf = (long)b * F + f;
    const long kvb = bf * 4 + h;

    __shared__ __align__(16) u16t s_p[4][16][168];

    const int l  = tid & 63;
    const int wv = tid >> 6;
    const int lr = l & 15;
    const int lq = l >> 4;
    const int qt0 = qb0 + wv * 16;

    // Q fragment (zero rows for lq>=2: d padded 16->32)
    bfrag Bq = (bfrag)0;
    if (lq < 2)
        Bq = *(const bfrag*)&qt[(bf * T + qt0 + lr) * 64 + h * 16 + lq * 8];

    // K fragments, direct from global
    bfrag Kf[9];
    const int pK0 = qt0 - 64 + lr;
#pragma unroll
    for (int kti = 0; kti < 9; kti++) {
        if (lq < 2)
            Kf[kti] = *(const bfrag*)&kt_[(kvb * T + pK0 + kti * 16) * 16 + lq * 8];
        else
            Kf[kti] = (bfrag)0;
    }
    // V fragments, direct from global (V^T [d][t]); p0 multiple of 8
    bfrag Vf[5];
    const int pV0 = qb0 - 64 + wv * 16 + lq * 8;
#pragma unroll
    for (int kc = 0; kc < 5; kc++)
        Vf[kc] = *(const bfrag*)&vt[(kvb * 16 + lr) * T + pV0 + kc * 32];

    if (qc == 0) {      // phantom keys p<0: K=0 (score 0, included), V=0
#pragma unroll
        for (int kti = 0; kti < 9; kti++)
            if (pK0 + kti * 16 < 0) Kf[kti] = (bfrag)0;
#pragma unroll
        for (int kc = 0; kc < 5; kc++)
            if (pV0 + kc * 32 < 0) Vf[kc] = (bfrag)0;
    }
    if (qc == 7) {      // right tail p>=T: V garbage guard (P=0 there)
#pragma unroll
        for (int kc = 0; kc < 5; kc++)
            if (pV0 + kc * 32 >= T) Vf[kc] = (bfrag)0;
    }

    f32x4 sf[9];
#pragma unroll
    for (int kti = 0; kti < 9; kti++)
        sf[kti] = __builtin_amdgcn_mfma_f32_16x16x32_bf16(
            Kf[kti], Bq, (f32x4){0.f, 0.f, 0.f, 0.f}, 0, 0, 0);

    float m = -3.0e38f;
    if (qc == 7) {
#pragma unroll
        for (int kti = 0; kti < 9; kti++)
#pragma unroll
            for (int j = 0; j < 4; j++) {
                int rk = kti * 16 + lq * 4 + j;
                int dq = rk - lr;
                int p  = qt0 - 64 + rk;
                float s = sf[kti][j];
                s = (dq >= 0 && dq <= 128 && p < T) ? s : -1.0e30f;
                sf[kti][j] = s;
                m = fmaxf(m, s);
            }
    } else {
        // band masks only on edge kti 0 (dq>=0) and 8 (dq<=128)
#pragma unroll
        for (int j = 0; j < 4; j++) {
            int rk0 = lq * 4 + j;
            if (rk0 < lr)      sf[0][j] = -1.0e30f;   // dq < 0
            if (rk0 > lr)      sf[8][j] = -1.0e30f;   // 128+rk0-lr > 128
        }
#pragma unroll
        for (int kti = 0; kti < 9; kti++)
#pragma unroll
            for (int j = 0; j < 4; j++) m = fmaxf(m, sf[kti][j]);
    }
    m = fmaxf(m, __shfl_xor(m, 16));
    m = fmaxf(m, __shfl_xor(m, 32));

    float lsum = 0.f;
#pragma unroll
    for (int kti = 0; kti < 9; kti++)
#pragma unroll
        for (int j = 0; j < 4; j++) {
            float e = exp2f(sf[kti][j] - m);
            sf[kti][j] = e;
            lsum += e;
        }
    lsum += __shfl_xor(lsum, 16);
    lsum += __shfl_xor(lsum, 32);

#pragma unroll
    for (int kti = 0; kti < 9; kti++) {
        ushort4 pk;
        pk.x = fbf(sf[kti][0]); pk.y = fbf(sf[kti][1]);
        pk.z = fbf(sf[kti][2]); pk.w = fbf(sf[kti][3]);
        *(ushort4*)&s_p[wv][lr][kti * 16 + lq * 4] = pk;
    }
    {
        ushort4 z; z.x = 0; z.y = 0; z.z = 0; z.w = 0;
        *(ushort4*)&s_p[wv][lr][144 + lq * 4] = z;   // zero tail rk 144..159
    }
    __syncthreads();

    f32x4 oa = (f32x4){0.f, 0.f, 0.f, 0.f};
#pragma unroll
    for (int kc = 0; kc < 5; kc++) {
        bfrag Bp = *(const bfrag*)&s_p[wv][lr][kc * 32 + lq * 8];
        oa = __builtin_amdgcn_mfma_f32_16x16x32_bf16(Vf[kc], Bp, oa, 0, 0, 0);
    }
    const float inv = 1.0f / lsum;
    ushort4 ov;
    ov.x = fbf(oa[0] * inv); ov.y = fbf(oa[1] * inv);
    ov.z = fbf(oa[2] * inv); ov.w = fbf(oa[3] * inv);
    *(ushort4*)&ob[(bf * T + qt0 + lr) * 64 + h * 16 + lq * 4] = ov;
}

// ---------------------------------------------------------------------------
// MFMA fused o-projection + BN + LeakyReLU + final conv1x1 (proven round 9).
// ---------------------------------------------------------------------------
__global__ __launch_bounds__(256) void final_mfma_k(
    const u16t* __restrict__ ob, const u16t* __restrict__ yb,
    const u16t* __restrict__ wo, const float* __restrict__ obias,
    const float* __restrict__ sg, const float* __restrict__ sb,
    const float* __restrict__ sm, const float* __restrict__ sv,
    const u16t* __restrict__ wsao, const float* __restrict__ swb,
    float* __restrict__ out)
{
    constexpr int F = 64, T = 512, TT = 64, P = 72;
    __shared__ __align__(16) u16t s_ob[64][P];
    __shared__ __align__(16) u16t s_y2[64][P];
    __shared__ __align__(16) u16t s_att[64][P];
    __shared__ float s_sc[128], s_sh[128];

    const int tid = threadIdx.x;
    const int t0 = blockIdx.x * TT;
    const int f = blockIdx.y, b = blockIdx.z;

    if (tid < 128) {
        float sc = sg[tid] * rsqrtf(sv[tid] + 1e-5f);
        s_sc[tid] = sc;
        s_sh[tid] = sb[tid] - sm[tid] * sc;
    }
    __syncthreads();

    for (int i = tid; i < 512; i += 256) {
        int tt = i >> 3, c0 = (i & 7) * 8;
        long gi = (((long)b * F + f) * T + t0 + tt) * 64 + c0;
        *(uh8*)&s_ob[tt][c0] = *(const uh8*)&ob[gi];
        uh8 raw = *(const uh8*)&yb[gi];
        uh8 v;
#pragma unroll
        for (int j = 0; j < 8; j++) {
            float xv = bfu(raw[j]);
            float xn = fmaf(xv, s_sc[c0 + j], s_sh[c0 + j]);
            v[j] = fbf(fmaxf(xn, 0.01f * xn));
        }
        *(uh8*)&s_y2[tt][c0] = v;
    }
    __syncthreads();

    const int l  = tid & 63;
    const int wv = tid >> 6;
    const int lr = l & 15;
    const int lq = l >> 4;
    const int tbase = wv * 16 + lr;
    const int cbase = lq * 8;

    f32x4 acc1[4];
#pragma unroll
    for (int i = 0; i < 4; i++) acc1[i] = (f32x4){0.f, 0.f, 0.f, 0.f};
#pragma unroll
    for (int kb = 0; kb < 2; kb++) {
        bfrag B = *(const bfrag*)&s_ob[tbase][kb * 32 + cbase];
#pragma unroll
        for (int ct = 0; ct < 4; ct++) {
            bfrag A = *(const bfrag*)&wo[(kb * 64 + ct * 16 + lr) * 32 + lq * 8];
            acc1[ct] = __builtin_amdgcn_mfma_f32_16x16x32_bf16(A, B, acc1[ct], 0, 0, 0);
        }
    }
#pragma unroll
    for (int ct = 0; ct < 4; ct++) {
        int co = ct * 16 + lq * 4;
        float4 bi = *(const float4*)&obias[co];
#pragma unroll
        for (int j = 0; j < 4; j++) {
            float a = acc1[ct][j] + ((j == 0) ? bi.x : (j == 1) ? bi.y : (j == 2) ? bi.z : bi.w);
            int cg = 64 + co + j;
            float xn = fmaf(a, s_sc[cg], s_sh[cg]);
            s_att[tbase][co + j] = fbf(fmaxf(xn, 0.01f * xn));
        }
    }
    __syncthreads();

    f32x4 acc2[4];
#pragma unroll
    for (int i = 0; i < 4; i++) acc2[i] = (f32x4){0.f, 0.f, 0.f, 0.f};
#pragma unroll
    for (int kb = 0; kb < 4; kb++) {
        bfrag B = (kb < 2) ? *(const bfrag*)&s_y2[tbase][kb * 32 + cbase]
                           : *(const bfrag*)&s_att[tbase][(kb - 2) * 32 + cbase];
#pragma unroll
        for (int ct = 0; ct < 4; ct++) {
            bfrag A = *(const bfrag*)&wsao[(kb * 64 + ct * 16 + lr) * 32 + lq * 8];
            acc2[ct] = __builtin_amdgcn_mfma_f32_16x16x32_bf16(A, B, acc2[ct], 0, 0, 0);
        }
    }
    const int t = t0 + wv * 16 + lr;
#pragma unroll
    for (int ct = 0; ct < 4; ct++) {
        int co0 = ct * 16 + lq * 4;
        float4 bs = *(const float4*)&swb[co0];
#pragma unroll
        for (int j = 0; j < 4; j++) {
            float bv = (j == 0) ? bs.x : (j == 1) ? bs.y : (j == 2) ? bs.z : bs.w;
            out[(((long)b * 64 + co0 + j) * F + f) * T + t] = acc2[ct][j] + bv;
        }
    }
}

// ---------------------------------------------------------------------------
extern "C" void kernel_launch(void* const* d_in, const int* in_sizes, int n_in,
                              void* d_out, int out_size, void* d_ws, size_t ws_size,
                              hipStream_t stream)
{
    (void)in_sizes; (void)n_in; (void)out_size; (void)ws_size;

    const float* x      = (const float*)d_in[0];
    const float* bd0_g  = (const float*)d_in[1];
    const float* bd0_b  = (const float*)d_in[2];
    const float* bd0_m  = (const float*)d_in[3];
    const float* bd0_v  = (const float*)d_in[4];
    const float* bd0_w  = (const float*)d_in[5];
    const float* bd0_wb = (const float*)d_in[6];
    const float* bd1_g  = (const float*)d_in[7];
    const float* bd1_b  = (const float*)d_in[8];
    const float* bd1_m  = (const float*)d_in[9];
    const float* bd1_v  = (const float*)d_in[10];
    const float* bd1_w  = (const float*)d_in[11];
    const float* bd1_wb = (const float*)d_in[12];
    const float* bdo_g  = (const float*)d_in[13];
    const float* bdo_b  = (const float*)d_in[14];
    const float* bdo_m  = (const float*)d_in[15];
    const float* bdo_v  = (const float*)d_in[16];
    const float* bdo_w  = (const float*)d_in[17];
    const float* bdo_wb = (const float*)d_in[18];
    const float* qkv_w  = (const float*)d_in[19];
    const float* qkv_b  = (const float*)d_in[20];
    const float* o_w    = (const float*)d_in[21];
    const float* o_b    = (const float*)d_in[22];
    const float* sao_g  = (const float*)d_in[23];
    const float* sao_b  = (const float*)d_in[24];
    const float* sao_m  = (const float*)d_in[25];
    const float* sao_v  = (const float*)d_in[26];
    const float* sao_w  = (const float*)d_in[27];
    const float* sao_wb = (const float*)d_in[28];

    char* ws = (char*)d_ws;
    // ws map (bytes), peak 75.8MB (ws >= 83.9MB proven by rounds 2/3):
    //   [0.0 , 16.8M)  xn0  -> ybf (conv2 out; xn0 dead after conv0)
    //   [16.8, 33.6M)  xn1  -> q_t (qkv out; xn1 dead) -> obf (in-place)
    //   [33.6, 50.3M)  xn2  -> k_t (xn2 dead after conv2)
    //   [50.3, 58.7M)  a0n1 \ -> v_t [50.3,67.1) (a0n* dead after conv1/2)
    //   [58.7, 67.1M)  a0n2 /
    //   [67.1, 75.5M)  a1n2
    //   [75.5, 75.8M)  wpack bf16 (144384 entries)
    u16t* xn0  = (u16t*)(ws);
    u16t* xn1  = (u16t*)(ws + 16777216);
    u16t* xn2  = (u16t*)(ws + 33554432);
    u16t* a0n1 = (u16t*)(ws + 50331648);
    u16t* a0n2 = (u16t*)(ws + 58720256);
    u16t* a1n2 = (u16t*)(ws + 67108864);
    u16t* ybf  = xn0;
    u16t* q_t  = xn1;
    u16t* k_t  = xn2;
    u16t* v_t  = a0n1;
    u16t* obf  = q_t;                      // in-place alias (proven)
    u16t* wpk  = (u16t*)(ws + 75497472);

    dim3 blk(256);
    dim3 gprep(8, 64, 4);   // T/64, F, B
    dim3 gconv(8, 16, 4);   // T/64, F/4, B

    hipLaunchKernelGGL(prep_x3_k, gprep, blk, 0, stream, x,
        bd0_g, bd0_b, bd0_m, bd0_v, bd1_g, bd1_b, bd1_m, bd1_v,
        bdo_g, bdo_b, bdo_m, bdo_v, xn0, xn1, xn2);
    hipLaunchKernelGGL(prep_w_k, dim3(564), blk, 0, stream,
        bd0_w, bd1_w, bdo_w, o_w, sao_w, qkv_w, wpk);
    hipLaunchKernelGGL((conv3x3_ff4_k<64, 32, 2>), gconv, blk, 0, stream,
        xn0, nullptr, nullptr, wpk, bd0_wb,
        bd1_g, bd1_b, bd1_m, bd1_v, bdo_g, bdo_b, bdo_m, bdo_v,
        64, a0n1, a0n2);
    hipLaunchKernelGGL((conv3x3_ff4_k<96, 32, 1>), gconv, blk, 0, stream,
        xn1, a0n1, nullptr, wpk + 18432, bd1_wb,
        bdo_g, bdo_b, bdo_m, bdo_v, nullptr, nullptr, nullptr, nullptr,
        96, a1n2, nullptr);
    hipLaunchKernelGGL((conv3x3_ff4_k<128, 64, 0>), gconv, blk, 0, stream,
        xn2, a0n2, a1n2, wpk + 46080, bdo_wb,
        nullptr, nullptr, nullptr, nullptr, nullptr, nullptr, nullptr, nullptr,
        0, ybf, nullptr);
    hipLaunchKernelGGL(qkv_mfma_k, gprep, blk, 0, stream,
        ybf, wpk + 132096, qkv_b, q_t, k_t, v_t);
    hipLaunchKernelGGL(attn_mfma_k, dim3(32, 64, 4), blk, 0, stream,
        q_t, k_t, v_t, obf);
    hipLaunchKernelGGL(final_mfma_k, gprep, blk, 0, stream,
        obf, ybf, wpk + 119808, o_b, sao_g, sao_b, sao_m, sao_v,
        wpk + 123904, sao_wb, (float*)d_out);
}